// Round 9
// baseline (190.547 us; speedup 1.0000x reference)
//
#include <hip/hip_runtime.h>
#include <hip/hip_bf16.h>
#include <math.h>

// Problem constants
#define DIM     192
#define HEADS   6
#define HEAD_DIM 32
#define NTOK    64          // tokens per window
#define IN_CC   16
#define TTOT    32768       // 8 * 64 * 64 tokens
#define NWIN    512

using bf16x8 = __attribute__((ext_vector_type(8))) short;
using f32x4  = __attribute__((ext_vector_type(4))) float;
typedef unsigned short ushort_t;

// ---------------------------------------------------------------------------
// TWO bf16 convert families (same RNE result, different codegen):
//  - f2bt/pk2t: bit-twiddle, short live ranges (attn phase at the 168-reg cap)
//  - f2b/pk2: native casts (prep / mlp phase — off the register cliff)
__device__ __forceinline__ ushort_t f2bt(float f) {
    unsigned u = __float_as_uint(f);
    u += 0x7fffu + ((u >> 16) & 1u);
    return (ushort_t)(u >> 16);
}
__device__ __forceinline__ unsigned pk2t(float a, float b) {
    return (unsigned)f2bt(a) | ((unsigned)f2bt(b) << 16);
}
__device__ __forceinline__ ushort_t f2b(float f) {
    __bf16 h = (__bf16)f;
    ushort_t u;
    __builtin_memcpy(&u, &h, 2);
    return u;
}
__device__ __forceinline__ unsigned pk2(float a, float b) {
    return (unsigned)f2b(a) | ((unsigned)f2b(b) << 16);
}
__device__ __forceinline__ float b2f(ushort_t u) {
    return __uint_as_float(((unsigned)u) << 16);
}
__device__ __forceinline__ float m3(float a, float b, float c) {
    return fmaxf(fmaxf(a, b), c);     // clang fuses to v_max3_f32
}
#define F4C(v, r) ((r) == 0 ? (v).x : (r) == 1 ? (v).y : (r) == 2 ? (v).z : (v).w)

// ---------------------------------------------------------------------------
// PREP kernel (unchanged): weight fp32->bf16 fragment-order conversion
// (432 blocks) merged with LN1+transpose (512 blocks).
__global__ __launch_bounds__(256) void prep_kernel(
    const float* __restrict__ s0, const float* __restrict__ s1,
    const float* __restrict__ s2, const float* __restrict__ s3,
    ushort_t* __restrict__ d0, ushort_t* __restrict__ d1,
    ushort_t* __restrict__ d2, ushort_t* __restrict__ d3,
    const float* __restrict__ x, const float* __restrict__ g,
    const float* __restrict__ bb, ushort_t* __restrict__ outh)
{
    __shared__ float xs[64][193];
    __shared__ float mu_s[64], rs_s[64];
    __shared__ float gs[192], bs[192];
    const int bid = blockIdx.x;
    const int tid = threadIdx.x;

    if (bid < 432) {
        const float* src; ushort_t* dst; int off, K; bool perm = false;
        if (bid < 108)      { src = s0; dst = d0; off = bid;       K = 192; perm = true; }
        else if (bid < 144) { src = s1; dst = d1; off = bid - 108; K = 192; }
        else if (bid < 288) { src = s2; dst = d2; off = bid - 144; K = 192; }
        else                { src = s3; dst = d3; off = bid - 288; K = 768; }
        const int K8 = K >> 3;
        const int d  = (off * 256 + tid) * 4;
        const int frag = d >> 7, win = d & 127;
        const int m16w = win >> 3, k7 = win & 7;
        const int oblk = frag / K8, kblk = frag - oblk * K8;
        const int o = oblk * 16 + m16w, k = kblk * 8 + k7;
        int so = o;
        if (perm && o < 384) {
            const int s = o & 31;
            const int c = (((s >> 2) & 3) << 3) | (((s >> 4) & 1) << 2) | (s & 3);
            so = (o & ~31) | c;
        }
        float4 v = *(const float4*)(src + (size_t)so * K + k);
        ushort4 ov;
        ov.x = f2b(v.x); ov.y = f2b(v.y); ov.z = f2b(v.z); ov.w = f2b(v.w);
        *(ushort4*)(dst + d) = ov;
        return;
    }

    const int t0  = (bid - 432) * 64;
    const int b   = t0 >> 12;
    const int hw0 = t0 & 4095;
    if (tid < 192) { gs[tid] = g[tid]; bs[tid] = bb[tid]; }
    const int tok = tid & 63, qq = tid >> 6;
    const float* xb = x + (size_t)b * (DIM * 4096) + hw0 + tok;
    #pragma unroll
    for (int it = 0; it < 48; ++it) {
        int c = it * 4 + qq;
        xs[tok][c] = xb[(size_t)c * 4096];
    }
    __syncthreads();
    const int tok2 = tid >> 2, p = tid & 3;
    float sum = 0.f;
    #pragma unroll
    for (int c = 0; c < 48; ++c) sum += xs[tok2][p * 48 + c];
    sum += __shfl_xor(sum, 1);
    sum += __shfl_xor(sum, 2);
    const float m = sum * (1.0f / 192.0f);
    float ss = 0.f;
    #pragma unroll
    for (int c = 0; c < 48; ++c) { float d = xs[tok2][p * 48 + c] - m; ss += d * d; }
    ss += __shfl_xor(ss, 1);
    ss += __shfl_xor(ss, 2);
    if (p == 0) {
        mu_s[tok2] = m;
        rs_s[tok2] = 1.0f / sqrtf(ss * (1.0f / 192.0f) + 1e-5f);
    }
    __syncthreads();
    ushort_t* obh = outh + (size_t)t0 * DIM;
    #pragma unroll
    for (int it = 0; it < 48; ++it) {
        int idx = it * 256 + tid;
        int tk = idx / 192, c = idx % 192;
        obh[idx] = f2b((xs[tk][c] - mu_s[tk]) * rs_s[tk] * gs[c] + bs[c]);
    }
}

// ---------------------------------------------------------------------------
// MEGA-FUSED attention + MLP: one block = 2 windows (128 tokens), 12 waves.
// x2 NEVER touches HBM: attn epilogue writes x2 f32 into LDS (x2L), the MLP
// phase (LN2 -> fc1+GELU -> fc2 -> +residual -> NCHW out) reads it there.
// Saves 75 MB of x2 traffic + one kernel launch; out writes become 32-B
// granule (window-scattered NCHW), an accepted ~+15 MB.
//
// LDS map (157184 B), hazard-checked per phase (barriers B1..B5 + mlp's):
//  [0,55296)       attn: 12 R-arenas (Ssq/Ph) + tile/AoT overlay 2x25600.
//                  mlp:  h_h[64][200] bf16 @0, a1c[64][200] bf16 @25600
//                        (first write after B5; AoT last read ends at B5).
//  [55296,155648)  x2L f32 [128][196] (first write after B4).  During attn
//                  pre-B3 the same region holds Ab arenas (Vt/ksb/qnb,
//                  [55296,116736)) and rpb ([116736,127648)) — all dead by B3.
//  [155648,157184) gs/bs (norm2 g,b) — written at kernel start, read post-B5.
__global__ __launch_bounds__(768, 3) void attn_mlp_fused(
    const ushort_t* __restrict__ sc_h, const ushort_t* __restrict__ wqf,
    const float* __restrict__ qkv_b, const float* __restrict__ rpb_table,
    const float* __restrict__ temp, const ushort_t* __restrict__ wpf,
    const float* __restrict__ proj_b, const ushort_t* __restrict__ w1f,
    const ushort_t* __restrict__ w2f, const float* __restrict__ fc1_b,
    const float* __restrict__ fc2_b, const float* __restrict__ g2,
    const float* __restrict__ b2, float* __restrict__ outp)
{
    __shared__ __align__(16) char smem[157184];
    const int tid  = threadIdx.x;
    const int wave = tid >> 6, n = tid & 63;

    char* Rb = smem + wave * 4608;
    float*    Ssq = (float*)Rb;                  // [16][68] f32 transpose qtr
    ushort_t* Ph  = (ushort_t*)Rb;               // [32][72] bf16 P half (ovl)
    char* Ab = smem + 55296 + wave * 5120;
    ushort_t* Vt  = (ushort_t*)Ab;               // [32][72] V^T slot-permuted
    float*    ksb = (float*)(Ab + 4608);         // [64] slot-ordered 1/||k||
    float*    qnb = (float*)(Ab + 4864);         // [64] ssq of q per token
    float*    rpb = (float*)(smem + 116736) + wave * 228;

    const int wloc = (wave >= 6) ? 1 : 0;        // window within block
    const int h    = wave - 6 * wloc;            // head
    ushort_t* tile = (ushort_t*)(smem + wloc * 25600);       // [64][200] bf16
    ushort_t (*AoT)[200] = (ushort_t(*)[200])(smem + wloc * 25600);
    float* x2L = (float*)(smem + 55296);         // [128][196] f32
    ushort_t (*h_h)[200] = (ushort_t(*)[200])smem;           // mlp overlay
    ushort_t (*a1c)[200] = (ushort_t(*)[200])(smem + 25600); // mlp overlay
    float* gs = (float*)(smem + 155648);
    float* bs = gs + 192;

    const int win = blockIdx.x * 2 + wloc;
    const int b   = win >> 6;
    const int wh  = (win >> 3) & 7, ww = win & 7;
    const int wb  = b * 4096 + wh * 512 + ww * 8;
    const int i1  = n >> 3, j1 = n & 7;
    const int m16 = n & 15, quad = n >> 4;

    if (tid < 192) { gs[tid] = g2[tid]; bs[tid] = b2[tid]; }
    for (int r = n; r < 225; r += 64) rpb[r] = rpb_table[r * 6 + h];

    // ---- phase 0: stage this window's shortcut tile into LDS (once) ----
    #pragma unroll
    for (int l = 0; l < 4; ++l) {
        const int g = h * 256 + l * 64 + n;
        const int t = (g * 2731) >> 16;          // g / 24
        const int r = g - t * 24;
        const int tt = wb + ((t >> 3) << 6) + (t & 7);
        uint4 v = *(const uint4*)(sc_h + (size_t)tt * 192 + r * 8);
        *(uint4*)(tile + t * 200 + r * 8) = v;
    }
    __syncthreads();                              // B1: tile ready

    // ---- phase 1a: q & k GEMMs sharing af fragments (all LDS reads) ----
    const ushort_t* tb = tile + m16 * 200 + quad * 8;
    f32x4 pq[4][2], pk[4][2];
    #pragma unroll
    for (int i = 0; i < 4; ++i)
        #pragma unroll
        for (int j = 0; j < 2; ++j) { pq[i][j] = (f32x4)(0.0f); pk[i][j] = (f32x4)(0.0f); }
    {
        const ushort_t* WbQ = wqf + (size_t)(2 * h) * 3072 + m16 * 8;
        const ushort_t* WbK = wqf + (size_t)(12 + 2 * h) * 3072 + m16 * 8;
        for (int ks = 0; ks < 192; ks += 32) {
            bf16x8 af[4], wq2[2], wk2[2];
            #pragma unroll
            for (int i = 0; i < 4; ++i)
                af[i] = *(const bf16x8*)(tb + i * 3200 + ks);
            #pragma unroll
            for (int j = 0; j < 2; ++j) {
                wq2[j] = *(const bf16x8*)(WbQ + (size_t)(j * 24 + (ks >> 3) + quad) * 128);
                wk2[j] = *(const bf16x8*)(WbK + (size_t)(j * 24 + (ks >> 3) + quad) * 128);
            }
            #pragma unroll
            for (int i = 0; i < 4; ++i)
                #pragma unroll
                for (int j = 0; j < 2; ++j) {
                    pq[i][j] = __builtin_amdgcn_mfma_f32_16x16x32_bf16(wq2[j], af[i], pq[i][j], 0, 0, 0);
                    pk[i][j] = __builtin_amdgcn_mfma_f32_16x16x32_bf16(wk2[j], af[i], pk[i][j], 0, 0, 0);
                }
        }
    }
    // q/k epilogue: bias, ssq, pack to QK^T fragments (permuted slots)
    bf16x8 qA[4], kB[4];
    #pragma unroll
    for (int part = 0; part < 2; ++part) {
        const int o0 = part * 192 + h * 32;
        const float4 bv0 = *(const float4*)&qkv_b[o0 + 8 * quad];
        const float4 bv1 = *(const float4*)&qkv_b[o0 + 8 * quad + 4];
        float ssq[4];
        #pragma unroll
        for (int i = 0; i < 4; ++i) {
            f32x4 v0 = part ? pk[i][0] : pq[i][0];
            f32x4 v1 = part ? pk[i][1] : pq[i][1];
            v0[0] += bv0.x; v0[1] += bv0.y; v0[2] += bv0.z; v0[3] += bv0.w;
            v1[0] += bv1.x; v1[1] += bv1.y; v1[2] += bv1.z; v1[3] += bv1.w;
            float sq = 0.f;
            #pragma unroll
            for (int r = 0; r < 4; ++r) sq += v0[r] * v0[r] + v1[r] * v1[r];
            ssq[i] = sq;
            bf16x8 fr;
            fr[0] = (short)f2bt(v0[0]); fr[1] = (short)f2bt(v0[1]);
            fr[2] = (short)f2bt(v0[2]); fr[3] = (short)f2bt(v0[3]);
            fr[4] = (short)f2bt(v1[0]); fr[5] = (short)f2bt(v1[1]);
            fr[6] = (short)f2bt(v1[2]); fr[7] = (short)f2bt(v1[3]);
            if (part == 0) qA[i] = fr; else kB[i] = fr;
        }
        #pragma unroll
        for (int i = 0; i < 4; ++i) {
            ssq[i] += __shfl_xor(ssq[i], 16);
            ssq[i] += __shfl_xor(ssq[i], 32);
        }
        if (quad == 0) {
            #pragma unroll
            for (int i = 0; i < 4; ++i) {
                if (part == 0) qnb[16 * i + m16] = ssq[i];
                else           ksb[4 * m16 + i]  = 1.0f / fmaxf(sqrtf(ssq[i]), 1e-12f);
            }
        }
    }

    // ---- phase 2: QK^T, register-to-register ----
    f32x4 acc[4][4];
    #pragma unroll
    for (int i = 0; i < 4; ++i)
        #pragma unroll
        for (int j = 0; j < 4; ++j)
            acc[i][j] = __builtin_amdgcn_mfma_f32_16x16x32_bf16(qA[i], kB[j], (f32x4)(0.0f), 0, 0, 0);

    // ---- phase 1b: v GEMM (af re-read from LDS) ----
    {
        f32x4 pv[4][2];
        #pragma unroll
        for (int i = 0; i < 4; ++i)
            #pragma unroll
            for (int j = 0; j < 2; ++j) pv[i][j] = (f32x4)(0.0f);
        const ushort_t* WbV = wqf + (size_t)(24 + 2 * h) * 3072 + m16 * 8;
        for (int ks = 0; ks < 192; ks += 32) {
            bf16x8 af[4], wv2[2];
            #pragma unroll
            for (int i = 0; i < 4; ++i)
                af[i] = *(const bf16x8*)(tb + i * 3200 + ks);
            #pragma unroll
            for (int j = 0; j < 2; ++j)
                wv2[j] = *(const bf16x8*)(WbV + (size_t)(j * 24 + (ks >> 3) + quad) * 128);
            #pragma unroll
            for (int i = 0; i < 4; ++i)
                #pragma unroll
                for (int j = 0; j < 2; ++j)
                    pv[i][j] = __builtin_amdgcn_mfma_f32_16x16x32_bf16(wv2[j], af[i], pv[i][j], 0, 0, 0);
        }
        const int o0 = 384 + h * 32;
        const float4 bv0 = *(const float4*)&qkv_b[o0 + quad * 4];
        const float4 bv1 = *(const float4*)&qkv_b[o0 + 16 + quad * 4];
        #pragma unroll
        for (int i = 0; i < 4; ++i) {
            f32x4 v0 = pv[i][0], v1 = pv[i][1];
            v0[0] += bv0.x; v0[1] += bv0.y; v0[2] += bv0.z; v0[3] += bv0.w;
            v1[0] += bv1.x; v1[1] += bv1.y; v1[2] += bv1.z; v1[3] += bv1.w;
            #pragma unroll
            for (int r = 0; r < 4; ++r) {
                Vt[(quad * 4 + r) * 72 + 4 * m16 + i]      = f2bt(v0[r]);
                Vt[(16 + quad * 4 + r) * 72 + 4 * m16 + i] = f2bt(v1[r]);
            }
        }
    }

    __syncthreads();                              // B2: tiles dead, R usable

    // ---- transpose S via 16-row quarter buffer (wave-local) ----
    float s[64];
    #pragma unroll
    for (int i = 0; i < 4; ++i) {
        #pragma unroll
        for (int r = 0; r < 4; ++r) {
            f32x4 vv = { acc[i][0][r], acc[i][1][r], acc[i][2][r], acc[i][3][r] };
            *(f32x4*)&Ssq[(4 * quad + r) * 68 + 4 * m16] = vv;
        }
        if ((n >> 4) == i) {
            #pragma unroll
            for (int c = 0; c < 16; ++c)
                *(float4*)&s[4 * c] = *(const float4*)&Ssq[(n & 15) * 68 + 4 * c];
        }
    }

    // ---- cosine scales ----
    const float qs = temp[h] / fmaxf(sqrtf(qnb[n]), 1e-12f);
    #pragma unroll
    for (int c = 0; c < 16; ++c) {
        float4 kv = *(const float4*)&ksb[4 * c];
        s[4*c+0] *= qs * kv.x; s[4*c+1] *= qs * kv.y;
        s[4*c+2] *= qs * kv.z; s[4*c+3] *= qs * kv.w;
    }

    // ---- top-16 threshold via masked v_max3 trees ----
    float thr = 1e30f;
    for (int it = 0; it < IN_CC; ++it) {
        #define MK(c) ((s[(c)] < thr) ? s[(c)] : -1e30f)
        float w[22];
        #pragma unroll
        for (int g = 0; g < 21; ++g) w[g] = m3(MK(3*g), MK(3*g+1), MK(3*g+2));
        w[21] = MK(63);
        #undef MK
        float y[8];
        #pragma unroll
        for (int g = 0; g < 7; ++g) y[g] = m3(w[3*g], w[3*g+1], w[3*g+2]);
        y[7] = w[21];
        thr = m3(m3(y[0], y[1], y[2]), m3(y[3], y[4], y[5]), fmaxf(y[6], y[7]));
    }

    // ---- mask + rpb + softmax (slot c holds true m = 16*(c&3)+(c>>2)) ----
    const int basen = i1 * 15 + j1;
    float mxp[8];
    #pragma unroll
    for (int c = 0; c < 64; ++c) {
        const int m = 16 * (c & 3) + (c >> 2);
        const int i2 = m >> 3, j2 = m & 7;
        float vv = ((s[c] >= thr) ? s[c] : -100.0f)
                 + rpb[basen + (7 - i2) * 15 + (7 - j2)];
        s[c] = vv;
        if (c < 8) mxp[c] = vv; else mxp[c & 7] = fmaxf(mxp[c & 7], vv);
    }
    const float mx = m3(m3(mxp[0], mxp[1], mxp[2]), m3(mxp[3], mxp[4], mxp[5]),
                        fmaxf(mxp[6], mxp[7]));
    float sum = 0.f;
    #pragma unroll
    for (int c = 0; c < 64; ++c) { float e = __expf(s[c] - mx); s[c] = e; sum += e; }
    const float inv = 1.0f / sum;
    #pragma unroll
    for (int c = 0; c < 64; ++c) s[c] *= inv;

    // ---- PV via MFMA, P staged in two 32-row halves (R overlay) ----
    bf16x8 vb[2][2];
    #pragma unroll
    for (int kh2 = 0; kh2 < 2; ++kh2)
        #pragma unroll
        for (int j2 = 0; j2 < 2; ++j2)
            vb[kh2][j2] = *(const bf16x8*)&Vt[(16 * j2 + m16) * 72 + kh2 * 32 + quad * 8];

    f32x4 o[4][2];
    #pragma unroll
    for (int i = 0; i < 4; ++i)
        #pragma unroll
        for (int j2 = 0; j2 < 2; ++j2)
            o[i][j2] = (f32x4)(0.0f);
    #pragma unroll
    for (int hf = 0; hf < 2; ++hf) {
        if ((n >> 5) == hf) {
            #pragma unroll
            for (int g = 0; g < 8; ++g) {
                uint4 w;
                w.x = pk2t(s[8*g+0], s[8*g+1]); w.y = pk2t(s[8*g+2], s[8*g+3]);
                w.z = pk2t(s[8*g+4], s[8*g+5]); w.w = pk2t(s[8*g+6], s[8*g+7]);
                *(uint4*)&Ph[(n & 31) * 72 + 8 * g] = w;
            }
        }
        #pragma unroll
        for (int ih = 0; ih < 2; ++ih) {
            const int i = 2 * hf + ih;
            #pragma unroll
            for (int kh2 = 0; kh2 < 2; ++kh2) {
                bf16x8 pafr = *(const bf16x8*)&Ph[(16 * ih + m16) * 72 + kh2 * 32 + quad * 8];
                o[i][0] = __builtin_amdgcn_mfma_f32_16x16x32_bf16(pafr, vb[kh2][0], o[i][0], 0, 0, 0);
                o[i][1] = __builtin_amdgcn_mfma_f32_16x16x32_bf16(pafr, vb[kh2][1], o[i][1], 0, 0, 0);
            }
        }
    }
    __syncthreads();   // B3: arenas dead -> AoT may overlay; x2L region free

    // ---- O -> shared AoT tile (bf16, token-major, stride 200) ----
    #pragma unroll
    for (int i = 0; i < 4; ++i) {
        #pragma unroll
        for (int r = 0; r < 4; ++r) {
            const int row = 16 * i + 4 * quad + r;
            AoT[row][h * 32 + m16]      = f2bt(o[i][0][r]);
            AoT[row][h * 32 + 16 + m16] = f2bt(o[i][1][r]);
        }
    }
    __syncthreads();   // B4

    // ---- residual prefetch (shortcut bf16): channels h*32+16j+quad*4..+3
    //      of tokens 16i+m16; hidden under the proj GEMM. ----
    uint2 rvv[4][2];
    #pragma unroll
    for (int i = 0; i < 4; ++i) {
        const int wtok = 16 * i + m16;
        const int tt = wb + ((wtok >> 3) << 6) + (wtok & 7);
        #pragma unroll
        for (int j = 0; j < 2; ++j)
            rvv[i][j] = *(const uint2*)&sc_h[(size_t)tt * 192 + h * 32 + 16 * j + quad * 4];
    }

    // ---- proj: wave computes outs [h*32, h*32+32) of its window, K=192 ----
    f32x4 pacc[4][2];
    #pragma unroll
    for (int i = 0; i < 4; ++i)
        #pragma unroll
        for (int j = 0; j < 2; ++j)
            pacc[i][j] = (f32x4)(0.0f);
    const ushort_t* Wb = wpf + (size_t)(h * 2) * 24 * 128 + m16 * 8;
    for (int ks = 0; ks < 192; ks += 32) {
        bf16x8 af[4], wv[2];
        #pragma unroll
        for (int i = 0; i < 4; ++i)
            af[i] = *(const bf16x8*)&AoT[16 * i + m16][quad * 8 + ks];
        #pragma unroll
        for (int j = 0; j < 2; ++j)
            wv[j] = *(const bf16x8*)(Wb + (size_t)(j * 24 + (ks >> 3) + quad) * 128);
        #pragma unroll
        for (int i = 0; i < 4; ++i)
            #pragma unroll
            for (int j = 0; j < 2; ++j)
                pacc[i][j] = __builtin_amdgcn_mfma_f32_16x16x32_bf16(wv[j], af[i], pacc[i][j], 0, 0, 0);
    }

    // ---- x2 = proj + bias + shortcut -> LDS x2L (f32, [128][196]) ----
    const float4 bj0 = *(const float4*)&proj_b[h * 32 + quad * 4];
    const float4 bj1 = *(const float4*)&proj_b[h * 32 + 16 + quad * 4];
    #pragma unroll
    for (int i = 0; i < 4; ++i) {
        f32x4 v0 = pacc[i][0], v1 = pacc[i][1];
        v0[0] += bj0.x; v0[1] += bj0.y; v0[2] += bj0.z; v0[3] += bj0.w;
        v1[0] += bj1.x; v1[1] += bj1.y; v1[2] += bj1.z; v1[3] += bj1.w;
        const uint2 r0 = rvv[i][0], r1 = rvv[i][1];
        v0[0] += b2f((ushort_t)(r0.x & 0xffffu)); v0[1] += b2f((ushort_t)(r0.x >> 16));
        v0[2] += b2f((ushort_t)(r0.y & 0xffffu)); v0[3] += b2f((ushort_t)(r0.y >> 16));
        v1[0] += b2f((ushort_t)(r1.x & 0xffffu)); v1[1] += b2f((ushort_t)(r1.x >> 16));
        v1[2] += b2f((ushort_t)(r1.y & 0xffffu)); v1[3] += b2f((ushort_t)(r1.y >> 16));
        float* xr = &x2L[(size_t)(wloc * 64 + 16 * i + m16) * 196 + h * 32 + quad * 4];
        *(f32x4*)xr        = v0;
        *(f32x4*)(xr + 16) = v1;
    }
    __syncthreads();   // B5: x2L complete; AoT dead -> h_h/a1c may overlay

    // ======================= MLP phase (2 passes x 64 tokens) ==============
    // wave = (th = wloc: 32-token half, ow = h: 32-out group)
    const int th = wloc, ow = h;
    for (int p = 0; p < 2; ++p) {
        // ---- LN2: 512 threads, 8 per token, 24 channels each ----
        if (tid < 512) {
            const int tok = tid >> 3, pp = tid & 7;
            const float* xr = &x2L[(size_t)(p * 64 + tok) * 196 + pp * 24];
            float xv[24];
            #pragma unroll
            for (int c6 = 0; c6 < 6; ++c6)
                *(float4*)&xv[c6 * 4] = *(const float4*)(xr + c6 * 4);
            float sum2 = 0.f;
            #pragma unroll
            for (int c = 0; c < 24; ++c) sum2 += xv[c];
            sum2 += __shfl_xor(sum2, 1);
            sum2 += __shfl_xor(sum2, 2);
            sum2 += __shfl_xor(sum2, 4);
            const float mm = sum2 * (1.0f / 192.0f);
            float ss2 = 0.f;
            #pragma unroll
            for (int c = 0; c < 24; ++c) { float d = xv[c] - mm; ss2 += d * d; }
            ss2 += __shfl_xor(ss2, 1);
            ss2 += __shfl_xor(ss2, 2);
            ss2 += __shfl_xor(ss2, 4);
            const float rs = 1.0f / sqrtf(ss2 * (1.0f / 192.0f) + 1e-5f);
            ushort_t* hp = &h_h[tok][pp * 24];
            #pragma unroll
            for (int c2 = 0; c2 < 12; ++c2) {
                float v0 = (xv[2*c2]   - mm) * rs * gs[pp * 24 + 2*c2]   + bs[pp * 24 + 2*c2];
                float v1 = (xv[2*c2+1] - mm) * rs * gs[pp * 24 + 2*c2+1] + bs[pp * 24 + 2*c2+1];
                *(unsigned*)(hp + 2 * c2) = pk2(v0, v1);
            }
        }
        __syncthreads();

        f32x4 acc2[2][2];
        #pragma unroll
        for (int i = 0; i < 2; ++i)
            #pragma unroll
            for (int j = 0; j < 2; ++j)
                acc2[i][j] = (f32x4)(0.0f);

        for (int c = 0; c < 4; ++c) {             // 4 chunks of 192 fc1-outs
            f32x4 acc1[2][2];
            #pragma unroll
            for (int i = 0; i < 2; ++i)
                #pragma unroll
                for (int j = 0; j < 2; ++j)
                    acc1[i][j] = (f32x4)(0.0f);
            const ushort_t* Wb1 = w1f + (size_t)(c * 12 + ow * 2) * 3072 + m16 * 8;
            for (int ks = 0; ks < 192; ks += 32) {
                bf16x8 af[2], wv[2];
                #pragma unroll
                for (int i = 0; i < 2; ++i)
                    af[i] = *(const bf16x8*)&h_h[th * 32 + 16 * i + m16][quad * 8 + ks];
                #pragma unroll
                for (int j = 0; j < 2; ++j)
                    wv[j] = *(const bf16x8*)(Wb1 + (size_t)(j * 24 + (ks >> 3) + quad) * 128);
                #pragma unroll
                for (int i = 0; i < 2; ++i)
                    #pragma unroll
                    for (int j = 0; j < 2; ++j)
                        acc1[i][j] = __builtin_amdgcn_mfma_f32_16x16x32_bf16(wv[j], af[i], acc1[i][j], 0, 0, 0);
            }
            #pragma unroll
            for (int j = 0; j < 2; ++j) {
                const int oo = c * 192 + ow * 32 + 16 * j + quad * 4;
                const float4 bv = *(const float4*)&fc1_b[oo];
                #pragma unroll
                for (int i = 0; i < 2; ++i) {
                    f32x4 v = acc1[i][j];
                    v[0] += bv.x; v[1] += bv.y; v[2] += bv.z; v[3] += bv.w;
                    #pragma unroll
                    for (int r = 0; r < 4; ++r) {
                        float xg = v[r];
                        float e1 = __expf(xg * (1.5957691f + 0.0713548f * xg * xg)) + 1.0f;
                        v[r] = xg - xg * __builtin_amdgcn_rcpf(e1);
                    }
                    uint2 pkd;
                    pkd.x = pk2(v[0], v[1]); pkd.y = pk2(v[2], v[3]);
                    *(uint2*)&a1c[th * 32 + 16 * i + m16][ow * 32 + 16 * j + quad * 4] = pkd;
                }
            }
            __syncthreads();
            const ushort_t* Wb2 = w2f + (size_t)(ow * 2) * 12288 + m16 * 8;
            for (int ks = 0; ks < 192; ks += 32) {
                bf16x8 af2[2], wv2[2];
                #pragma unroll
                for (int i = 0; i < 2; ++i)
                    af2[i] = *(const bf16x8*)&a1c[th * 32 + 16 * i + m16][quad * 8 + ks];
                #pragma unroll
                for (int j = 0; j < 2; ++j)
                    wv2[j] = *(const bf16x8*)(Wb2 + (size_t)(j * 96 + c * 24 + (ks >> 3) + quad) * 128);
                #pragma unroll
                for (int i = 0; i < 2; ++i)
                    #pragma unroll
                    for (int j = 0; j < 2; ++j)
                        acc2[i][j] = __builtin_amdgcn_mfma_f32_16x16x32_bf16(wv2[j], af2[i], acc2[i][j], 0, 0, 0);
            }
            __syncthreads();
        }

        // ---- pass epilogue: out = x2 + fc2out + bias, NCHW direct ----
        const int winp = blockIdx.x * 2 + p;
        const int bb2 = winp >> 6, whp = (winp >> 3) & 7, wwp = winp & 7;
        float* outb = outp + (size_t)bb2 * (DIM * 4096);
        #pragma unroll
        for (int j = 0; j < 2; ++j) {
            const float4 b2v = *(const float4*)&fc2_b[ow * 32 + 16 * j + quad * 4];
            #pragma unroll
            for (int i = 0; i < 2; ++i) {
                const int wtok = th * 32 + 16 * i + m16;
                const int hw = (whp * 8 + (wtok >> 3)) * 64 + wwp * 8 + (wtok & 7);
                const float* xrr = &x2L[(size_t)(p * 64 + wtok) * 196];
                #pragma unroll
                for (int r = 0; r < 4; ++r) {
                    const int oo = ow * 32 + 16 * j + quad * 4 + r;
                    outb[(size_t)oo * 4096 + hw] =
                        acc2[i][j][r] + F4C(b2v, r) + xrr[oo];
                }
            }
        }
        // no barrier needed: next pass's LN2 writes h_h (disjoint from x2L /
        // global); a1c rewrites are guarded by the chunk-loop barriers.
    }
}

// ---------------------------------------------------------------------------
extern "C" void kernel_launch(void* const* d_in, const int* in_sizes, int n_in,
                              void* d_out, int out_size, void* d_ws, size_t ws_size,
                              hipStream_t stream)
{
    const float* x        = (const float*)d_in[0];
    const float* norm1_g  = (const float*)d_in[1];
    const float* norm1_b  = (const float*)d_in[2];
    const float* qkv_w    = (const float*)d_in[3];
    const float* qkv_b    = (const float*)d_in[4];
    const float* proj_w   = (const float*)d_in[5];
    const float* proj_b   = (const float*)d_in[6];
    const float* rpbt     = (const float*)d_in[7];
    const float* temp     = (const float*)d_in[8];
    const float* norm2_g  = (const float*)d_in[9];
    const float* norm2_b  = (const float*)d_in[10];
    const float* fc1_w    = (const float*)d_in[11];
    const float* fc1_b    = (const float*)d_in[12];
    const float* fc2_w    = (const float*)d_in[13];
    const float* fc2_b    = (const float*)d_in[14];
    float* out = (float*)d_out;

    // ws layout (bytes):
    //   [0,        12582912)  shortcut bf16 (LN1 out)
    //   [125829120,...)       weights bf16 (fragment order; qkv Q/K permuted)
    //   (x2 no longer exists in HBM — it lives in LDS inside the fused kernel)
    char* wsb = (char*)d_ws;
    ushort_t* shortcut_h = (ushort_t*)wsb;
    ushort_t* wq  = (ushort_t*)(wsb + 125829120);      // 576x192 = 110592
    ushort_t* wp  = wq + 110592;                       // 192x192 = 36864
    ushort_t* w1  = wp + 36864;                        // 768x192 = 147456
    ushort_t* w2  = w1 + 147456;                       // 192x768 = 147456

    // 0+1. merged weight conversion (432 blocks) + LN1 transpose (512 blocks)
    hipLaunchKernelGGL(prep_kernel, dim3(432 + TTOT / 64), dim3(256), 0, stream,
                       qkv_w, proj_w, fc1_w, fc2_w, wq, wp, w1, w2,
                       x, norm1_g, norm1_b, shortcut_h);
    // 2. fused qkv + attention + proj + LN2 + MLP + residual -> out (NCHW)
    hipLaunchKernelGGL(attn_mlp_fused, dim3(NWIN / 2), dim3(768), 0, stream,
                       shortcut_h, wq, qkv_b, rpbt, temp, wp, proj_b,
                       w1, w2, fc1_b, fc2_b, norm2_g, norm2_b, out);
}

// Round 10
// 189.412 us; speedup vs baseline: 1.0060x; 1.0060x over previous
//
#include <hip/hip_runtime.h>
#include <hip/hip_bf16.h>
#include <math.h>

// Problem constants
#define DIM     192
#define HEADS   6
#define HEAD_DIM 32
#define NTOK    64          // tokens per window
#define IN_CC   16
#define TTOT    32768       // 8 * 64 * 64 tokens
#define NWIN    512

using bf16x8 = __attribute__((ext_vector_type(8))) short;
using f32x4  = __attribute__((ext_vector_type(4))) float;
typedef unsigned short ushort_t;

// ---------------------------------------------------------------------------
// TWO bf16 convert families (same RNE result, different codegen):
//  - f2bt/pk2t: bit-twiddle, short live ranges (attn phase at the 168-reg cap)
//  - f2b/pk2: native casts (prep / mlp — off the register cliff)
__device__ __forceinline__ ushort_t f2bt(float f) {
    unsigned u = __float_as_uint(f);
    u += 0x7fffu + ((u >> 16) & 1u);
    return (ushort_t)(u >> 16);
}
__device__ __forceinline__ unsigned pk2t(float a, float b) {
    return (unsigned)f2bt(a) | ((unsigned)f2bt(b) << 16);
}
__device__ __forceinline__ ushort_t f2b(float f) {
    __bf16 h = (__bf16)f;
    ushort_t u;
    __builtin_memcpy(&u, &h, 2);
    return u;
}
__device__ __forceinline__ unsigned pk2(float a, float b) {
    return (unsigned)f2b(a) | ((unsigned)f2b(b) << 16);
}
__device__ __forceinline__ float b2f(ushort_t u) {
    return __uint_as_float(((unsigned)u) << 16);
}
__device__ __forceinline__ float m3(float a, float b, float c) {
    return fmaxf(fmaxf(a, b), c);     // clang fuses to v_max3_f32
}

// ---------------------------------------------------------------------------
// PREP kernel (unchanged, round-8 validated): weight fp32->bf16 fragment-order
// conversion (432 blocks) merged with LN1+transpose (512 blocks).
__global__ __launch_bounds__(256) void prep_kernel(
    const float* __restrict__ s0, const float* __restrict__ s1,
    const float* __restrict__ s2, const float* __restrict__ s3,
    ushort_t* __restrict__ d0, ushort_t* __restrict__ d1,
    ushort_t* __restrict__ d2, ushort_t* __restrict__ d3,
    const float* __restrict__ x, const float* __restrict__ g,
    const float* __restrict__ bb, ushort_t* __restrict__ outh)
{
    __shared__ float xs[64][193];
    __shared__ float mu_s[64], rs_s[64];
    __shared__ float gs[192], bs[192];
    const int bid = blockIdx.x;
    const int tid = threadIdx.x;

    if (bid < 432) {
        const float* src; ushort_t* dst; int off, K; bool perm = false;
        if (bid < 108)      { src = s0; dst = d0; off = bid;       K = 192; perm = true; }
        else if (bid < 144) { src = s1; dst = d1; off = bid - 108; K = 192; }
        else if (bid < 288) { src = s2; dst = d2; off = bid - 144; K = 192; }
        else                { src = s3; dst = d3; off = bid - 288; K = 768; }
        const int K8 = K >> 3;
        const int d  = (off * 256 + tid) * 4;
        const int frag = d >> 7, win = d & 127;
        const int m16w = win >> 3, k7 = win & 7;
        const int oblk = frag / K8, kblk = frag - oblk * K8;
        const int o = oblk * 16 + m16w, k = kblk * 8 + k7;
        int so = o;
        if (perm && o < 384) {
            const int s = o & 31;
            const int c = (((s >> 2) & 3) << 3) | (((s >> 4) & 1) << 2) | (s & 3);
            so = (o & ~31) | c;
        }
        float4 v = *(const float4*)(src + (size_t)so * K + k);
        ushort4 ov;
        ov.x = f2b(v.x); ov.y = f2b(v.y); ov.z = f2b(v.z); ov.w = f2b(v.w);
        *(ushort4*)(dst + d) = ov;
        return;
    }

    const int t0  = (bid - 432) * 64;
    const int b   = t0 >> 12;
    const int hw0 = t0 & 4095;
    if (tid < 192) { gs[tid] = g[tid]; bs[tid] = bb[tid]; }
    const int tok = tid & 63, qq = tid >> 6;
    const float* xb = x + (size_t)b * (DIM * 4096) + hw0 + tok;
    #pragma unroll
    for (int it = 0; it < 48; ++it) {
        int c = it * 4 + qq;
        xs[tok][c] = xb[(size_t)c * 4096];
    }
    __syncthreads();
    const int tok2 = tid >> 2, p = tid & 3;
    float sum = 0.f;
    #pragma unroll
    for (int c = 0; c < 48; ++c) sum += xs[tok2][p * 48 + c];
    sum += __shfl_xor(sum, 1);
    sum += __shfl_xor(sum, 2);
    const float m = sum * (1.0f / 192.0f);
    float ss = 0.f;
    #pragma unroll
    for (int c = 0; c < 48; ++c) { float d = xs[tok2][p * 48 + c] - m; ss += d * d; }
    ss += __shfl_xor(ss, 1);
    ss += __shfl_xor(ss, 2);
    if (p == 0) {
        mu_s[tok2] = m;
        rs_s[tok2] = 1.0f / sqrtf(ss * (1.0f / 192.0f) + 1e-5f);
    }
    __syncthreads();
    ushort_t* obh = outh + (size_t)t0 * DIM;
    #pragma unroll
    for (int it = 0; it < 48; ++it) {
        int idx = it * 256 + tid;
        int tk = idx / 192, c = idx % 192;
        obh[idx] = f2b((xs[tk][c] - mu_s[tk]) * rs_s[tk] * gs[c] + bs[c]);
    }
}

// ---------------------------------------------------------------------------
// MEGA-FUSED attention — round-8 version verbatim (49.2 us validated).
__global__ __launch_bounds__(768, 3) void attn_fused(
    const ushort_t* __restrict__ sc_h, const ushort_t* __restrict__ wqf,
    const float* __restrict__ qkv_b, const float* __restrict__ rpb_table,
    const float* __restrict__ temp, const ushort_t* __restrict__ wpf,
    const float* __restrict__ proj_b, float* __restrict__ x2)
{
    __shared__ __align__(16) char smem[127680];
    const int tid  = threadIdx.x;
    const int wave = tid >> 6, n = tid & 63;

    char* Rb = smem + wave * 4608;
    float*    Ssq = (float*)Rb;                  // [16][68] f32 transpose qtr
    ushort_t* Ph  = (ushort_t*)Rb;               // [32][72] bf16 P half (ovl)
    char* Ab = smem + 55296 + wave * 5120;
    ushort_t* Vt  = (ushort_t*)Ab;               // [32][72] V^T slot-permuted
    float*    ksb = (float*)(Ab + 4608);         // [64] slot-ordered 1/||k||
    float*    qnb = (float*)(Ab + 4864);         // [64] ssq of q per token
    float*    rpb = (float*)(smem + 116736) + wave * 228;

    const int wloc = (wave >= 6) ? 1 : 0;        // window within block
    const int h    = wave - 6 * wloc;            // head
    ushort_t* tile = (ushort_t*)(smem + wloc * 25600);       // [64][200] bf16
    ushort_t (*AoT)[200] = (ushort_t(*)[200])(smem + wloc * 25600);
    float* Cwi = (float*)(smem + 55296 + wave * 2304);       // [16][36] f32

    const int win = blockIdx.x * 2 + wloc;
    const int b   = win >> 6;
    const int wh  = (win >> 3) & 7, ww = win & 7;
    const int wb  = b * 4096 + wh * 512 + ww * 8;
    const int i1  = n >> 3, j1 = n & 7;
    const int m16 = n & 15, quad = n >> 4;

    for (int r = n; r < 225; r += 64) rpb[r] = rpb_table[r * 6 + h];

    // ---- phase 0: stage this window's shortcut tile into LDS (once) ----
    #pragma unroll
    for (int l = 0; l < 4; ++l) {
        const int g = h * 256 + l * 64 + n;
        const int t = (g * 2731) >> 16;          // g / 24
        const int r = g - t * 24;
        const int tt = wb + ((t >> 3) << 6) + (t & 7);
        uint4 v = *(const uint4*)(sc_h + (size_t)tt * 192 + r * 8);
        *(uint4*)(tile + t * 200 + r * 8) = v;
    }
    __syncthreads();                              // B1: tile ready

    // ---- phase 1a: q & k GEMMs sharing af fragments (all LDS reads) ----
    const ushort_t* tb = tile + m16 * 200 + quad * 8;
    f32x4 pq[4][2], pk[4][2];
    #pragma unroll
    for (int i = 0; i < 4; ++i)
        #pragma unroll
        for (int j = 0; j < 2; ++j) { pq[i][j] = (f32x4)(0.0f); pk[i][j] = (f32x4)(0.0f); }
    {
        const ushort_t* WbQ = wqf + (size_t)(2 * h) * 3072 + m16 * 8;
        const ushort_t* WbK = wqf + (size_t)(12 + 2 * h) * 3072 + m16 * 8;
        for (int ks = 0; ks < 192; ks += 32) {
            bf16x8 af[4], wq2[2], wk2[2];
            #pragma unroll
            for (int i = 0; i < 4; ++i)
                af[i] = *(const bf16x8*)(tb + i * 3200 + ks);
            #pragma unroll
            for (int j = 0; j < 2; ++j) {
                wq2[j] = *(const bf16x8*)(WbQ + (size_t)(j * 24 + (ks >> 3) + quad) * 128);
                wk2[j] = *(const bf16x8*)(WbK + (size_t)(j * 24 + (ks >> 3) + quad) * 128);
            }
            #pragma unroll
            for (int i = 0; i < 4; ++i)
                #pragma unroll
                for (int j = 0; j < 2; ++j) {
                    pq[i][j] = __builtin_amdgcn_mfma_f32_16x16x32_bf16(wq2[j], af[i], pq[i][j], 0, 0, 0);
                    pk[i][j] = __builtin_amdgcn_mfma_f32_16x16x32_bf16(wk2[j], af[i], pk[i][j], 0, 0, 0);
                }
        }
    }
    // q/k epilogue: bias, ssq, pack to QK^T fragments (permuted slots)
    bf16x8 qA[4], kB[4];
    #pragma unroll
    for (int part = 0; part < 2; ++part) {
        const int o0 = part * 192 + h * 32;
        const float4 bv0 = *(const float4*)&qkv_b[o0 + 8 * quad];
        const float4 bv1 = *(const float4*)&qkv_b[o0 + 8 * quad + 4];
        float ssq[4];
        #pragma unroll
        for (int i = 0; i < 4; ++i) {
            f32x4 v0 = part ? pk[i][0] : pq[i][0];
            f32x4 v1 = part ? pk[i][1] : pq[i][1];
            v0[0] += bv0.x; v0[1] += bv0.y; v0[2] += bv0.z; v0[3] += bv0.w;
            v1[0] += bv1.x; v1[1] += bv1.y; v1[2] += bv1.z; v1[3] += bv1.w;
            float sq = 0.f;
            #pragma unroll
            for (int r = 0; r < 4; ++r) sq += v0[r] * v0[r] + v1[r] * v1[r];
            ssq[i] = sq;
            bf16x8 fr;
            fr[0] = (short)f2bt(v0[0]); fr[1] = (short)f2bt(v0[1]);
            fr[2] = (short)f2bt(v0[2]); fr[3] = (short)f2bt(v0[3]);
            fr[4] = (short)f2bt(v1[0]); fr[5] = (short)f2bt(v1[1]);
            fr[6] = (short)f2bt(v1[2]); fr[7] = (short)f2bt(v1[3]);
            if (part == 0) qA[i] = fr; else kB[i] = fr;
        }
        #pragma unroll
        for (int i = 0; i < 4; ++i) {
            ssq[i] += __shfl_xor(ssq[i], 16);
            ssq[i] += __shfl_xor(ssq[i], 32);
        }
        if (quad == 0) {
            #pragma unroll
            for (int i = 0; i < 4; ++i) {
                if (part == 0) qnb[16 * i + m16] = ssq[i];
                else           ksb[4 * m16 + i]  = 1.0f / fmaxf(sqrtf(ssq[i]), 1e-12f);
            }
        }
    }

    // ---- phase 2: QK^T, register-to-register ----
    f32x4 acc[4][4];
    #pragma unroll
    for (int i = 0; i < 4; ++i)
        #pragma unroll
        for (int j = 0; j < 4; ++j)
            acc[i][j] = __builtin_amdgcn_mfma_f32_16x16x32_bf16(qA[i], kB[j], (f32x4)(0.0f), 0, 0, 0);

    // ---- phase 1b: v GEMM (af re-read from LDS) ----
    {
        f32x4 pv[4][2];
        #pragma unroll
        for (int i = 0; i < 4; ++i)
            #pragma unroll
            for (int j = 0; j < 2; ++j) pv[i][j] = (f32x4)(0.0f);
        const ushort_t* WbV = wqf + (size_t)(24 + 2 * h) * 3072 + m16 * 8;
        for (int ks = 0; ks < 192; ks += 32) {
            bf16x8 af[4], wv2[2];
            #pragma unroll
            for (int i = 0; i < 4; ++i)
                af[i] = *(const bf16x8*)(tb + i * 3200 + ks);
            #pragma unroll
            for (int j = 0; j < 2; ++j)
                wv2[j] = *(const bf16x8*)(WbV + (size_t)(j * 24 + (ks >> 3) + quad) * 128);
            #pragma unroll
            for (int i = 0; i < 4; ++i)
                #pragma unroll
                for (int j = 0; j < 2; ++j)
                    pv[i][j] = __builtin_amdgcn_mfma_f32_16x16x32_bf16(wv2[j], af[i], pv[i][j], 0, 0, 0);
        }
        const int o0 = 384 + h * 32;
        const float4 bv0 = *(const float4*)&qkv_b[o0 + quad * 4];
        const float4 bv1 = *(const float4*)&qkv_b[o0 + 16 + quad * 4];
        #pragma unroll
        for (int i = 0; i < 4; ++i) {
            f32x4 v0 = pv[i][0], v1 = pv[i][1];
            v0[0] += bv0.x; v0[1] += bv0.y; v0[2] += bv0.z; v0[3] += bv0.w;
            v1[0] += bv1.x; v1[1] += bv1.y; v1[2] += bv1.z; v1[3] += bv1.w;
            #pragma unroll
            for (int r = 0; r < 4; ++r) {
                Vt[(quad * 4 + r) * 72 + 4 * m16 + i]      = f2bt(v0[r]);
                Vt[(16 + quad * 4 + r) * 72 + 4 * m16 + i] = f2bt(v1[r]);
            }
        }
    }

    __syncthreads();                              // B2: tiles dead, R usable

    // ---- transpose S via 16-row quarter buffer (wave-local) ----
    float s[64];
    #pragma unroll
    for (int i = 0; i < 4; ++i) {
        #pragma unroll
        for (int r = 0; r < 4; ++r) {
            f32x4 vv = { acc[i][0][r], acc[i][1][r], acc[i][2][r], acc[i][3][r] };
            *(f32x4*)&Ssq[(4 * quad + r) * 68 + 4 * m16] = vv;
        }
        if ((n >> 4) == i) {
            #pragma unroll
            for (int c = 0; c < 16; ++c)
                *(float4*)&s[4 * c] = *(const float4*)&Ssq[(n & 15) * 68 + 4 * c];
        }
    }

    // ---- cosine scales (positive; preserve top-k ordering) ----
    const float qs = temp[h] / fmaxf(sqrtf(qnb[n]), 1e-12f);
    #pragma unroll
    for (int c = 0; c < 16; ++c) {
        float4 kv = *(const float4*)&ksb[4 * c];
        s[4*c+0] *= qs * kv.x; s[4*c+1] *= qs * kv.y;
        s[4*c+2] *= qs * kv.z; s[4*c+3] *= qs * kv.w;
    }

    // ---- top-16 threshold via masked v_max3 trees (bit-identical) ----
    float thr = 1e30f;
    for (int it = 0; it < IN_CC; ++it) {
        #define MK(c) ((s[(c)] < thr) ? s[(c)] : -1e30f)
        float w[22];
        #pragma unroll
        for (int g = 0; g < 21; ++g) w[g] = m3(MK(3*g), MK(3*g+1), MK(3*g+2));
        w[21] = MK(63);
        #undef MK
        float y[8];
        #pragma unroll
        for (int g = 0; g < 7; ++g) y[g] = m3(w[3*g], w[3*g+1], w[3*g+2]);
        y[7] = w[21];
        thr = m3(m3(y[0], y[1], y[2]), m3(y[3], y[4], y[5]), fmaxf(y[6], y[7]));
    }

    // ---- mask + rpb + softmax (slot c holds true m = 16*(c&3)+(c>>2)) ----
    const int basen = i1 * 15 + j1;
    float mxp[8];
    #pragma unroll
    for (int c = 0; c < 64; ++c) {
        const int m = 16 * (c & 3) + (c >> 2);
        const int i2 = m >> 3, j2 = m & 7;
        float vv = ((s[c] >= thr) ? s[c] : -100.0f)
                 + rpb[basen + (7 - i2) * 15 + (7 - j2)];
        s[c] = vv;
        if (c < 8) mxp[c] = vv; else mxp[c & 7] = fmaxf(mxp[c & 7], vv);
    }
    const float mx = m3(m3(mxp[0], mxp[1], mxp[2]), m3(mxp[3], mxp[4], mxp[5]),
                        fmaxf(mxp[6], mxp[7]));
    float sum = 0.f;
    #pragma unroll
    for (int c = 0; c < 64; ++c) { float e = __expf(s[c] - mx); s[c] = e; sum += e; }
    const float inv = 1.0f / sum;
    #pragma unroll
    for (int c = 0; c < 64; ++c) s[c] *= inv;

    // ---- PV via MFMA, P staged in two 32-row halves (R overlay) ----
    bf16x8 vb[2][2];
    #pragma unroll
    for (int kh2 = 0; kh2 < 2; ++kh2)
        #pragma unroll
        for (int j2 = 0; j2 < 2; ++j2)
            vb[kh2][j2] = *(const bf16x8*)&Vt[(16 * j2 + m16) * 72 + kh2 * 32 + quad * 8];

    f32x4 o[4][2];
    #pragma unroll
    for (int i = 0; i < 4; ++i)
        #pragma unroll
        for (int j2 = 0; j2 < 2; ++j2)
            o[i][j2] = (f32x4)(0.0f);
    #pragma unroll
    for (int hf = 0; hf < 2; ++hf) {
        if ((n >> 5) == hf) {
            #pragma unroll
            for (int g = 0; g < 8; ++g) {
                uint4 w;
                w.x = pk2t(s[8*g+0], s[8*g+1]); w.y = pk2t(s[8*g+2], s[8*g+3]);
                w.z = pk2t(s[8*g+4], s[8*g+5]); w.w = pk2t(s[8*g+6], s[8*g+7]);
                *(uint4*)&Ph[(n & 31) * 72 + 8 * g] = w;
            }
        }
        #pragma unroll
        for (int ih = 0; ih < 2; ++ih) {
            const int i = 2 * hf + ih;
            #pragma unroll
            for (int kh2 = 0; kh2 < 2; ++kh2) {
                bf16x8 pafr = *(const bf16x8*)&Ph[(16 * ih + m16) * 72 + kh2 * 32 + quad * 8];
                o[i][0] = __builtin_amdgcn_mfma_f32_16x16x32_bf16(pafr, vb[kh2][0], o[i][0], 0, 0, 0);
                o[i][1] = __builtin_amdgcn_mfma_f32_16x16x32_bf16(pafr, vb[kh2][1], o[i][1], 0, 0, 0);
            }
        }
    }
    __syncthreads();   // B3: all waves done with arenas -> AoT may overlay

    // ---- O -> shared AoT tile (bf16, token-major, stride 200) ----
    #pragma unroll
    for (int i = 0; i < 4; ++i) {
        #pragma unroll
        for (int r = 0; r < 4; ++r) {
            const int row = 16 * i + 4 * quad + r;
            AoT[row][h * 32 + m16]      = f2bt(o[i][0][r]);
            AoT[row][h * 32 + 16 + m16] = f2bt(o[i][1][r]);
        }
    }
    __syncthreads();   // B4

    // ---- residual prefetch: AFTER B4, low-pressure region ----
    const int r8 = n >> 3, c4 = (n & 7) * 4;
    uint2 rv[4][2];
    #pragma unroll
    for (int i = 0; i < 4; ++i)
        #pragma unroll
        for (int q = 0; q < 2; ++q) {
            const int tok = 16 * i + 8 * q + r8;
            const int tt = wb + ((tok >> 3) << 6) + (tok & 7);
            rv[i][q] = *(const uint2*)(sc_h + (size_t)tt * 192 + h * 32 + c4);
        }

    // ---- proj: wave computes outs [h*32, h*32+32) of its window, K=192 ----
    f32x4 pacc[4][2];
    #pragma unroll
    for (int i = 0; i < 4; ++i)
        #pragma unroll
        for (int j = 0; j < 2; ++j)
            pacc[i][j] = (f32x4)(0.0f);
    const ushort_t* Wb = wpf + (size_t)(h * 2) * 24 * 128 + m16 * 8;
    for (int ks = 0; ks < 192; ks += 32) {
        bf16x8 af[4], wv[2];
        #pragma unroll
        for (int i = 0; i < 4; ++i)
            af[i] = *(const bf16x8*)&AoT[16 * i + m16][quad * 8 + ks];
        #pragma unroll
        for (int j = 0; j < 2; ++j)
            wv[j] = *(const bf16x8*)(Wb + (size_t)(j * 24 + (ks >> 3) + quad) * 128);
        #pragma unroll
        for (int i = 0; i < 4; ++i)
            #pragma unroll
            for (int j = 0; j < 2; ++j)
                pacc[i][j] = __builtin_amdgcn_mfma_f32_16x16x32_bf16(wv[j], af[i], pacc[i][j], 0, 0, 0);
    }

    // ---- per i-group: stage C^T (+bias) into Cwi[16][36]; store x2 with
    //      full 128-B-granule coverage per instruction. ----
    const float4 bj0 = *(const float4*)&proj_b[h * 32 + quad * 4];
    const float4 bj1 = *(const float4*)&proj_b[h * 32 + 16 + quad * 4];
    #pragma unroll
    for (int i = 0; i < 4; ++i) {
        f32x4 v0 = pacc[i][0], v1 = pacc[i][1];
        v0[0] += bj0.x; v0[1] += bj0.y; v0[2] += bj0.z; v0[3] += bj0.w;
        v1[0] += bj1.x; v1[1] += bj1.y; v1[2] += bj1.z; v1[3] += bj1.w;
        *(f32x4*)&Cwi[m16 * 36 + quad * 4]      = v0;
        *(f32x4*)&Cwi[m16 * 36 + 16 + quad * 4] = v1;
        #pragma unroll
        for (int q = 0; q < 2; ++q) {
            const int row = 8 * q + r8;
            const int tok = 16 * i + row;
            const int tt = wb + ((tok >> 3) << 6) + (tok & 7);
            float4 vv = *(const float4*)&Cwi[row * 36 + c4];
            const uint2 rr = rv[i][q];
            vv.x += b2f((ushort_t)(rr.x & 0xffffu));
            vv.y += b2f((ushort_t)(rr.x >> 16));
            vv.z += b2f((ushort_t)(rr.y & 0xffffu));
            vv.w += b2f((ushort_t)(rr.y >> 16));
            *(float4*)&x2[(size_t)tt * DIM + h * 32 + c4] = vv;
        }
    }
}

// ---------------------------------------------------------------------------
// FUSED MLP v3: round-8 structure + DOUBLE-BUFFERED a1c.
// fc1(chunk c+1 -> other buffer) and fc2(chunk c <- current buffer) share one
// barrier interval: barriers 9 -> 6, and fc1's global weight loads hide under
// fc2's LDS+MFMA stream (mlp is latency/barrier-bound, proven by round-9's
// traffic-elimination null result).
// LDS: h_h[128][200] 51200 | a1c x2 [128][200] 102400 | gs/bs 1536 = 155136.
// Cw epilogue staging (12 x 4608 = 55296) overlays h_h + a1cA head after the
// final chunk barrier (all a1c reads complete).
__global__ __launch_bounds__(768, 3) void mlp_fused(
    const float* __restrict__ x2, const ushort_t* __restrict__ w1f,
    const ushort_t* __restrict__ w2f, const float* __restrict__ fc1_b,
    const float* __restrict__ fc2_b, const float* __restrict__ g2,
    const float* __restrict__ b2, float* __restrict__ outp)
{
    __shared__ __align__(16) char smem[155136];
    ushort_t (*h_h)[200] = (ushort_t(*)[200])smem;             // [128][200]
    ushort_t (*a1A)[200] = (ushort_t(*)[200])(smem + 51200);   // [128][200]
    ushort_t (*a1B)[200] = (ushort_t(*)[200])(smem + 102400);  // [128][200]
    float* gs = (float*)(smem + 153600);
    float* bs = gs + 192;

    const int tid  = threadIdx.x;
    const int wave = tid >> 6, lane = tid & 63;
    const int m16 = lane & 15, quad = lane >> 4;
    const int half = wave / 6, ow = wave - 6 * half;   // token-half, out-group
    const int t0  = blockIdx.x * 128;
    const int b   = t0 >> 12;
    const int hw0 = t0 & 4095;

    if (tid < 192) { gs[tid] = g2[tid]; bs[tid] = b2[tid]; }
    __syncthreads();
    if (tid < 512) {
        const int tok = tid >> 2, p = tid & 3;
        const float* rp = x2 + (size_t)(t0 + tok) * DIM + p * 48;
        float xv[48];
        #pragma unroll
        for (int c4 = 0; c4 < 12; ++c4)
            *(float4*)&xv[c4 * 4] = *(const float4*)(rp + c4 * 4);
        float sum = 0.f;
        #pragma unroll
        for (int c = 0; c < 48; ++c) sum += xv[c];
        sum += __shfl_xor(sum, 1);
        sum += __shfl_xor(sum, 2);
        const float m = sum * (1.0f / 192.0f);
        float ss = 0.f;
        #pragma unroll
        for (int c = 0; c < 48; ++c) { float d = xv[c] - m; ss += d * d; }
        ss += __shfl_xor(ss, 1);
        ss += __shfl_xor(ss, 2);
        const float rs = 1.0f / sqrtf(ss * (1.0f / 192.0f) + 1e-5f);
        ushort_t* hp = &h_h[tok][p * 48];
        #pragma unroll
        for (int c2 = 0; c2 < 24; ++c2) {
            float v0 = (xv[2*c2]   - m) * rs * gs[p * 48 + 2*c2]   + bs[p * 48 + 2*c2];
            float v1 = (xv[2*c2+1] - m) * rs * gs[p * 48 + 2*c2+1] + bs[p * 48 + 2*c2+1];
            *(unsigned*)(hp + 2 * c2) = pk2(v0, v1);
        }
    }
    __syncthreads();

    // fc1 of chunk c into dst; GELU'd bf16 result.
    auto fc1_chunk = [&](int c, ushort_t (*dst)[200]) {
        f32x4 acc1[4][2];
        #pragma unroll
        for (int i = 0; i < 4; ++i)
            #pragma unroll
            for (int j = 0; j < 2; ++j)
                acc1[i][j] = (f32x4)(0.0f);
        const ushort_t* Wb1 = w1f + (size_t)(c * 12 + ow * 2) * 3072 + m16 * 8;
        for (int ks = 0; ks < 192; ks += 32) {
            bf16x8 af[4], wv[2];
            #pragma unroll
            for (int i = 0; i < 4; ++i)
                af[i] = *(const bf16x8*)&h_h[half * 64 + 16 * i + m16][quad * 8 + ks];
            #pragma unroll
            for (int j = 0; j < 2; ++j)
                wv[j] = *(const bf16x8*)(Wb1 + (size_t)(j * 24 + (ks >> 3) + quad) * 128);
            #pragma unroll
            for (int i = 0; i < 4; ++i)
                #pragma unroll
                for (int j = 0; j < 2; ++j)
                    acc1[i][j] = __builtin_amdgcn_mfma_f32_16x16x32_bf16(wv[j], af[i], acc1[i][j], 0, 0, 0);
        }
        #pragma unroll
        for (int j = 0; j < 2; ++j) {
            const int o = c * 192 + ow * 32 + 16 * j + quad * 4;
            const float4 bv = *(const float4*)&fc1_b[o];
            #pragma unroll
            for (int i = 0; i < 4; ++i) {
                f32x4 v = acc1[i][j];
                v[0] += bv.x; v[1] += bv.y; v[2] += bv.z; v[3] += bv.w;
                #pragma unroll
                for (int r = 0; r < 4; ++r) {
                    float xg = v[r];
                    float e1 = __expf(xg * (1.5957691f + 0.0713548f * xg * xg)) + 1.0f;
                    v[r] = xg - xg * __builtin_amdgcn_rcpf(e1);
                }
                uint2 pkd;
                pkd.x = pk2(v[0], v[1]); pkd.y = pk2(v[2], v[3]);
                *(uint2*)&dst[half * 64 + 16 * i + m16][ow * 32 + 16 * j + quad * 4] = pkd;
            }
        }
    };

    f32x4 acc2[4][2];
    #pragma unroll
    for (int i = 0; i < 4; ++i)
        #pragma unroll
        for (int j = 0; j < 2; ++j)
            acc2[i][j] = (f32x4)(0.0f);

    fc1_chunk(0, a1A);
    __syncthreads();                              // a1A ready

    const ushort_t* Wb2 = w2f + (size_t)(ow * 2) * 12288 + m16 * 8;
    for (int c = 0; c < 4; ++c) {
        ushort_t (*cur)[200] = (c & 1) ? a1B : a1A;
        ushort_t (*nxt)[200] = (c & 1) ? a1A : a1B;
        // issue next chunk's fc1 first (global weight loads go out early),
        // then fc2 of current chunk (LDS+MFMA hides the load latency).
        if (c < 3) fc1_chunk(c + 1, nxt);
        for (int ks = 0; ks < 192; ks += 32) {
            bf16x8 af2[4], wv2[2];
            #pragma unroll
            for (int i = 0; i < 4; ++i)
                af2[i] = *(const bf16x8*)&cur[half * 64 + 16 * i + m16][quad * 8 + ks];
            #pragma unroll
            for (int j = 0; j < 2; ++j)
                wv2[j] = *(const bf16x8*)(Wb2 + (size_t)(j * 96 + c * 24 + (ks >> 3) + quad) * 128);
            #pragma unroll
            for (int i = 0; i < 4; ++i)
                #pragma unroll
                for (int j = 0; j < 2; ++j)
                    acc2[i][j] = __builtin_amdgcn_mfma_f32_16x16x32_bf16(wv2[j], af2[i], acc2[i][j], 0, 0, 0);
        }
        __syncthreads();   // nxt ready for next iter; cur reads all complete
    }

    // ---- epilogue: stage [32 tok][32 outs] per pass, write NCHW with
    //      full 128-B-granule runs (64-token-consecutive per channel). ----
    float* Cw = (float*)(smem + wave * 4608);      // [32][36] f32, overlay
    float4 b2j[2];
    #pragma unroll
    for (int j = 0; j < 2; ++j)
        b2j[j] = *(const float4*)&fc2_b[ow * 32 + 16 * j + quad * 4];
    #pragma unroll
    for (int p = 0; p < 2; ++p) {
        #pragma unroll
        for (int ih = 0; ih < 2; ++ih) {
            const int i = 2 * p + ih;
            #pragma unroll
            for (int j = 0; j < 2; ++j) {
                f32x4 v = acc2[i][j];
                v[0] += b2j[j].x; v[1] += b2j[j].y; v[2] += b2j[j].z; v[3] += b2j[j].w;
                *(f32x4*)&Cw[(ih * 16 + m16) * 36 + 16 * j + quad * 4] = v;
            }
        }
        #pragma unroll
        for (int q = 0; q < 4; ++q) {
            const int idx = q * 64 + lane;
            const int cc = idx >> 3, t4 = (idx & 7) * 4;
            const int o  = ow * 32 + cc;
            const int tb = t0 + half * 64 + p * 32 + t4;
            float4 vv;
            vv.x = Cw[(t4 + 0) * 36 + cc] + x2[(size_t)(tb + 0) * DIM + o];
            vv.y = Cw[(t4 + 1) * 36 + cc] + x2[(size_t)(tb + 1) * DIM + o];
            vv.z = Cw[(t4 + 2) * 36 + cc] + x2[(size_t)(tb + 2) * DIM + o];
            vv.w = Cw[(t4 + 3) * 36 + cc] + x2[(size_t)(tb + 3) * DIM + o];
            *(float4*)&outp[(size_t)b * (DIM * 4096) + (size_t)o * 4096
                            + hw0 + half * 64 + p * 32 + t4] = vv;
        }
    }
}

// ---------------------------------------------------------------------------
extern "C" void kernel_launch(void* const* d_in, const int* in_sizes, int n_in,
                              void* d_out, int out_size, void* d_ws, size_t ws_size,
                              hipStream_t stream)
{
    const float* x        = (const float*)d_in[0];
    const float* norm1_g  = (const float*)d_in[1];
    const float* norm1_b  = (const float*)d_in[2];
    const float* qkv_w    = (const float*)d_in[3];
    const float* qkv_b    = (const float*)d_in[4];
    const float* proj_w   = (const float*)d_in[5];
    const float* proj_b   = (const float*)d_in[6];
    const float* rpbt     = (const float*)d_in[7];
    const float* temp     = (const float*)d_in[8];
    const float* norm2_g  = (const float*)d_in[9];
    const float* norm2_b  = (const float*)d_in[10];
    const float* fc1_w    = (const float*)d_in[11];
    const float* fc1_b    = (const float*)d_in[12];
    const float* fc2_w    = (const float*)d_in[13];
    const float* fc2_b    = (const float*)d_in[14];
    float* out = (float*)d_out;

    // ws layout (bytes), COMPACTED (round-10): total footprint 38.2 MB.
    //   [0,        12582912)  shortcut bf16 (LN1 out)
    //   [12582912, 37748736)  x2 f32
    //   [37748736, ...)       weights bf16 (fragment order; qkv Q/K permuted)
    char* wsb = (char*)d_ws;
    ushort_t* shortcut_h = (ushort_t*)wsb;
    float*    x2         = (float*)(wsb + 12582912);
    ushort_t* wq  = (ushort_t*)(wsb + 37748736);       // 576x192 = 110592
    ushort_t* wp  = wq + 110592;                       // 192x192 = 36864
    ushort_t* w1  = wp + 36864;                        // 768x192 = 147456
    ushort_t* w2  = w1 + 147456;                       // 192x768 = 147456

    // 0+1. merged weight conversion (432 blocks) + LN1 transpose (512 blocks)
    hipLaunchKernelGGL(prep_kernel, dim3(432 + TTOT / 64), dim3(256), 0, stream,
                       qkv_w, proj_w, fc1_w, fc2_w, wq, wp, w1, w2,
                       x, norm1_g, norm1_b, shortcut_h);
    // 2. fused qkv + attention + proj + residual -> x2 (2 windows/block)
    hipLaunchKernelGGL(attn_fused, dim3(NWIN / 2), dim3(768), 0, stream,
                       shortcut_h, wq, qkv_b, rpbt, temp, wp, proj_b, x2);
    // 3. fused LN2 + fc1 + GELU + fc2 + residual + NCHW transpose
    //    (v3: double-buffered a1c, 6 barriers, fc1/fc2 overlap)
    hipLaunchKernelGGL(mlp_fused, dim3(TTOT / 128), dim3(768), 0, stream,
                       x2, w1, w2, fc1_b, fc2_b, norm2_g, norm2_b, out);
}

// Round 12
// 188.863 us; speedup vs baseline: 1.0089x; 1.0029x over previous
//
#include <hip/hip_runtime.h>
#include <hip/hip_bf16.h>
#include <math.h>

// Problem constants
#define DIM     192
#define HEADS   6
#define HEAD_DIM 32
#define NTOK    64          // tokens per window
#define IN_CC   16
#define TTOT    32768       // 8 * 64 * 64 tokens
#define NWIN    512

using bf16x8 = __attribute__((ext_vector_type(8))) short;
using f32x4  = __attribute__((ext_vector_type(4))) float;
typedef unsigned short ushort_t;

// ---------------------------------------------------------------------------
// TWO bf16 convert families (same RNE result, different codegen):
//  - f2bt/pk2t: bit-twiddle, short live ranges.  Used in attn_fused, which
//    sits at the 168-reg cap (min-waves=3): round-7 showed the native-cast
//    path (compiler pairs v_cvt_pk_bf16_f32, keeping both f32 sources live)
//    re-triggered ~6 MB of scratch spill there.
//  - f2b/pk2: native casts.  Used in prep/mlp (far from the reg cliff),
//    where fewer VALU ops won round-7's −4 us on the non-attn share.
__device__ __forceinline__ ushort_t f2bt(float f) {
    unsigned u = __float_as_uint(f);
    u += 0x7fffu + ((u >> 16) & 1u);
    return (ushort_t)(u >> 16);
}
__device__ __forceinline__ unsigned pk2t(float a, float b) {
    return (unsigned)f2bt(a) | ((unsigned)f2bt(b) << 16);
}
__device__ __forceinline__ ushort_t f2b(float f) {
    __bf16 h = (__bf16)f;
    ushort_t u;
    __builtin_memcpy(&u, &h, 2);
    return u;
}
__device__ __forceinline__ unsigned pk2(float a, float b) {
    return (unsigned)f2b(a) | ((unsigned)f2b(b) << 16);
}
__device__ __forceinline__ float b2f(ushort_t u) {
    return __uint_as_float(((unsigned)u) << 16);
}
__device__ __forceinline__ float m3(float a, float b, float c) {
    return fmaxf(fmaxf(a, b), c);     // clang fuses to v_max3_f32
}

// ---------------------------------------------------------------------------
// PREP kernel: weight fp32->bf16 fragment-order conversion (432 blocks)
// MERGED with LN1+transpose (512 blocks).
// cvt part: W (NxK row-major) -> W' where element (o,k) lives at
//   frag = (o/16)*(K/8) + (k/8);  W'[frag*128 + (o%16)*8 + (k%8)]
// qkv weight ONLY: Q and K parts (rows [0,384)) get a within-head output-row
// permutation so the qkv GEMM's C-fragment IS the QK^T MFMA A/B fragment
// (slot s=16j+4q+r holds natural channel c=8q+4j+r). QK^T is invariant under
// a common channel permutation of q and k.
__global__ __launch_bounds__(256) void prep_kernel(
    const float* __restrict__ s0, const float* __restrict__ s1,
    const float* __restrict__ s2, const float* __restrict__ s3,
    ushort_t* __restrict__ d0, ushort_t* __restrict__ d1,
    ushort_t* __restrict__ d2, ushort_t* __restrict__ d3,
    const float* __restrict__ x, const float* __restrict__ g,
    const float* __restrict__ bb, ushort_t* __restrict__ outh)
{
    __shared__ float xs[64][193];
    __shared__ float mu_s[64], rs_s[64];
    __shared__ float gs[192], bs[192];
    const int bid = blockIdx.x;
    const int tid = threadIdx.x;

    if (bid < 432) {
        // ---------------- weight conversion ----------------
        const float* src; ushort_t* dst; int off, K; bool perm = false;
        if (bid < 108)      { src = s0; dst = d0; off = bid;       K = 192; perm = true; }
        else if (bid < 144) { src = s1; dst = d1; off = bid - 108; K = 192; }
        else if (bid < 288) { src = s2; dst = d2; off = bid - 144; K = 192; }
        else                { src = s3; dst = d3; off = bid - 288; K = 768; }
        const int K8 = K >> 3;
        const int d  = (off * 256 + tid) * 4;
        const int frag = d >> 7, win = d & 127;
        const int m16w = win >> 3, k7 = win & 7;
        const int oblk = frag / K8, kblk = frag - oblk * K8;
        const int o = oblk * 16 + m16w, k = kblk * 8 + k7;
        int so = o;
        if (perm && o < 384) {
            const int s = o & 31;                       // slot within head block
            const int c = (((s >> 2) & 3) << 3) | (((s >> 4) & 1) << 2) | (s & 3);
            so = (o & ~31) | c;                         // natural channel row
        }
        float4 v = *(const float4*)(src + (size_t)so * K + k);
        ushort4 ov;
        ov.x = f2b(v.x); ov.y = f2b(v.y); ov.z = f2b(v.z); ov.w = f2b(v.w);
        *(ushort4*)(dst + d) = ov;
        return;
    }

    // ---------------- LN1 + (B,C,H,W)->(T,C) transpose, bf16 out ----------------
    const int t0  = (bid - 432) * 64;
    const int b   = t0 >> 12;
    const int hw0 = t0 & 4095;
    if (tid < 192) { gs[tid] = g[tid]; bs[tid] = bb[tid]; }
    const int tok = tid & 63, qq = tid >> 6;
    const float* xb = x + (size_t)b * (DIM * 4096) + hw0 + tok;
    #pragma unroll
    for (int it = 0; it < 48; ++it) {
        int c = it * 4 + qq;
        xs[tok][c] = xb[(size_t)c * 4096];
    }
    __syncthreads();
    const int tok2 = tid >> 2, p = tid & 3;
    float sum = 0.f;
    #pragma unroll
    for (int c = 0; c < 48; ++c) sum += xs[tok2][p * 48 + c];
    sum += __shfl_xor(sum, 1);
    sum += __shfl_xor(sum, 2);
    const float m = sum * (1.0f / 192.0f);
    float ss = 0.f;
    #pragma unroll
    for (int c = 0; c < 48; ++c) { float d = xs[tok2][p * 48 + c] - m; ss += d * d; }
    ss += __shfl_xor(ss, 1);
    ss += __shfl_xor(ss, 2);
    if (p == 0) {
        mu_s[tok2] = m;
        rs_s[tok2] = 1.0f / sqrtf(ss * (1.0f / 192.0f) + 1e-5f);
    }
    __syncthreads();
    ushort_t* obh = outh + (size_t)t0 * DIM;
    #pragma unroll
    for (int it = 0; it < 48; ++it) {
        int idx = it * 256 + tid;
        int tk = idx / 192, c = idx % 192;
        obh[idx] = f2b((xs[tk][c] - mu_s[tk]) * rs_s[tk] * gs[c] + bs[c]);
    }
}

// ---------------------------------------------------------------------------
// MEGA-FUSED attention — round-8 validated version (49.2 us, WRITE 31.5 MB):
// bit-twiddle converts (f2bt/pk2t), scalar Vt writes.
__global__ __launch_bounds__(768, 3) void attn_fused(
    const ushort_t* __restrict__ sc_h, const ushort_t* __restrict__ wqf,
    const float* __restrict__ qkv_b, const float* __restrict__ rpb_table,
    const float* __restrict__ temp, const ushort_t* __restrict__ wpf,
    const float* __restrict__ proj_b, float* __restrict__ x2)
{
    __shared__ __align__(16) char smem[127680];
    const int tid  = threadIdx.x;
    const int wave = tid >> 6, n = tid & 63;

    char* Rb = smem + wave * 4608;
    float*    Ssq = (float*)Rb;                  // [16][68] f32 transpose qtr
    ushort_t* Ph  = (ushort_t*)Rb;               // [32][72] bf16 P half (ovl)
    char* Ab = smem + 55296 + wave * 5120;
    ushort_t* Vt  = (ushort_t*)Ab;               // [32][72] V^T slot-permuted
    float*    ksb = (float*)(Ab + 4608);         // [64] slot-ordered 1/||k||
    float*    qnb = (float*)(Ab + 4864);         // [64] ssq of q per token
    float*    rpb = (float*)(smem + 116736) + wave * 228;

    const int wloc = (wave >= 6) ? 1 : 0;        // window within block
    const int h    = wave - 6 * wloc;            // head
    ushort_t* tile = (ushort_t*)(smem + wloc * 25600);       // [64][200] bf16
    ushort_t (*AoT)[200] = (ushort_t(*)[200])(smem + wloc * 25600);
    float* Cwi = (float*)(smem + 55296 + wave * 2304);       // [16][36] f32

    const int win = blockIdx.x * 2 + wloc;
    const int b   = win >> 6;
    const int wh  = (win >> 3) & 7, ww = win & 7;
    const int wb  = b * 4096 + wh * 512 + ww * 8;
    const int i1  = n >> 3, j1 = n & 7;
    const int m16 = n & 15, quad = n >> 4;

    for (int r = n; r < 225; r += 64) rpb[r] = rpb_table[r * 6 + h];

    // ---- phase 0: stage this window's shortcut tile into LDS (once) ----
    #pragma unroll
    for (int l = 0; l < 4; ++l) {
        const int g = h * 256 + l * 64 + n;
        const int t = (g * 2731) >> 16;          // g / 24
        const int r = g - t * 24;
        const int tt = wb + ((t >> 3) << 6) + (t & 7);
        uint4 v = *(const uint4*)(sc_h + (size_t)tt * 192 + r * 8);
        *(uint4*)(tile + t * 200 + r * 8) = v;
    }
    __syncthreads();                              // B1: tile ready

    // ---- phase 1a: q & k GEMMs sharing af fragments (all LDS reads) ----
    const ushort_t* tb = tile + m16 * 200 + quad * 8;
    f32x4 pq[4][2], pk[4][2];
    #pragma unroll
    for (int i = 0; i < 4; ++i)
        #pragma unroll
        for (int j = 0; j < 2; ++j) { pq[i][j] = (f32x4)(0.0f); pk[i][j] = (f32x4)(0.0f); }
    {
        const ushort_t* WbQ = wqf + (size_t)(2 * h) * 3072 + m16 * 8;
        const ushort_t* WbK = wqf + (size_t)(12 + 2 * h) * 3072 + m16 * 8;
        for (int ks = 0; ks < 192; ks += 32) {
            bf16x8 af[4], wq2[2], wk2[2];
            #pragma unroll
            for (int i = 0; i < 4; ++i)
                af[i] = *(const bf16x8*)(tb + i * 3200 + ks);
            #pragma unroll
            for (int j = 0; j < 2; ++j) {
                wq2[j] = *(const bf16x8*)(WbQ + (size_t)(j * 24 + (ks >> 3) + quad) * 128);
                wk2[j] = *(const bf16x8*)(WbK + (size_t)(j * 24 + (ks >> 3) + quad) * 128);
            }
            #pragma unroll
            for (int i = 0; i < 4; ++i)
                #pragma unroll
                for (int j = 0; j < 2; ++j) {
                    pq[i][j] = __builtin_amdgcn_mfma_f32_16x16x32_bf16(wq2[j], af[i], pq[i][j], 0, 0, 0);
                    pk[i][j] = __builtin_amdgcn_mfma_f32_16x16x32_bf16(wk2[j], af[i], pk[i][j], 0, 0, 0);
                }
        }
    }
    // q/k epilogue: bias, ssq, pack to QK^T fragments (permuted slots)
    bf16x8 qA[4], kB[4];
    #pragma unroll
    for (int part = 0; part < 2; ++part) {
        const int o0 = part * 192 + h * 32;
        const float4 bv0 = *(const float4*)&qkv_b[o0 + 8 * quad];
        const float4 bv1 = *(const float4*)&qkv_b[o0 + 8 * quad + 4];
        float ssq[4];
        #pragma unroll
        for (int i = 0; i < 4; ++i) {
            f32x4 v0 = part ? pk[i][0] : pq[i][0];
            f32x4 v1 = part ? pk[i][1] : pq[i][1];
            v0[0] += bv0.x; v0[1] += bv0.y; v0[2] += bv0.z; v0[3] += bv0.w;
            v1[0] += bv1.x; v1[1] += bv1.y; v1[2] += bv1.z; v1[3] += bv1.w;
            float sq = 0.f;
            #pragma unroll
            for (int r = 0; r < 4; ++r) sq += v0[r] * v0[r] + v1[r] * v1[r];
            ssq[i] = sq;
            bf16x8 fr;
            fr[0] = (short)f2bt(v0[0]); fr[1] = (short)f2bt(v0[1]);
            fr[2] = (short)f2bt(v0[2]); fr[3] = (short)f2bt(v0[3]);
            fr[4] = (short)f2bt(v1[0]); fr[5] = (short)f2bt(v1[1]);
            fr[6] = (short)f2bt(v1[2]); fr[7] = (short)f2bt(v1[3]);
            if (part == 0) qA[i] = fr; else kB[i] = fr;
        }
        #pragma unroll
        for (int i = 0; i < 4; ++i) {
            ssq[i] += __shfl_xor(ssq[i], 16);
            ssq[i] += __shfl_xor(ssq[i], 32);
        }
        if (quad == 0) {
            #pragma unroll
            for (int i = 0; i < 4; ++i) {
                if (part == 0) qnb[16 * i + m16] = ssq[i];
                else           ksb[4 * m16 + i]  = 1.0f / fmaxf(sqrtf(ssq[i]), 1e-12f);
            }
        }
    }

    // ---- phase 2: QK^T, register-to-register ----
    f32x4 acc[4][4];
    #pragma unroll
    for (int i = 0; i < 4; ++i)
        #pragma unroll
        for (int j = 0; j < 4; ++j)
            acc[i][j] = __builtin_amdgcn_mfma_f32_16x16x32_bf16(qA[i], kB[j], (f32x4)(0.0f), 0, 0, 0);

    // ---- phase 1b: v GEMM (af re-read from LDS) ----
    {
        f32x4 pv[4][2];
        #pragma unroll
        for (int i = 0; i < 4; ++i)
            #pragma unroll
            for (int j = 0; j < 2; ++j) pv[i][j] = (f32x4)(0.0f);
        const ushort_t* WbV = wqf + (size_t)(24 + 2 * h) * 3072 + m16 * 8;
        for (int ks = 0; ks < 192; ks += 32) {
            bf16x8 af[4], wv2[2];
            #pragma unroll
            for (int i = 0; i < 4; ++i)
                af[i] = *(const bf16x8*)(tb + i * 3200 + ks);
            #pragma unroll
            for (int j = 0; j < 2; ++j)
                wv2[j] = *(const bf16x8*)(WbV + (size_t)(j * 24 + (ks >> 3) + quad) * 128);
            #pragma unroll
            for (int i = 0; i < 4; ++i)
                #pragma unroll
                for (int j = 0; j < 2; ++j)
                    pv[i][j] = __builtin_amdgcn_mfma_f32_16x16x32_bf16(wv2[j], af[i], pv[i][j], 0, 0, 0);
        }
        const int o0 = 384 + h * 32;
        const float4 bv0 = *(const float4*)&qkv_b[o0 + quad * 4];
        const float4 bv1 = *(const float4*)&qkv_b[o0 + 16 + quad * 4];
        #pragma unroll
        for (int i = 0; i < 4; ++i) {
            f32x4 v0 = pv[i][0], v1 = pv[i][1];
            v0[0] += bv0.x; v0[1] += bv0.y; v0[2] += bv0.z; v0[3] += bv0.w;
            v1[0] += bv1.x; v1[1] += bv1.y; v1[2] += bv1.z; v1[3] += bv1.w;
            #pragma unroll
            for (int r = 0; r < 4; ++r) {
                Vt[(quad * 4 + r) * 72 + 4 * m16 + i]      = f2bt(v0[r]);
                Vt[(16 + quad * 4 + r) * 72 + 4 * m16 + i] = f2bt(v1[r]);
            }
        }
    }

    __syncthreads();                              // B2: tiles dead, R usable

    // ---- transpose S via 16-row quarter buffer (wave-local) ----
    float s[64];
    #pragma unroll
    for (int i = 0; i < 4; ++i) {
        #pragma unroll
        for (int r = 0; r < 4; ++r) {
            f32x4 vv = { acc[i][0][r], acc[i][1][r], acc[i][2][r], acc[i][3][r] };
            *(f32x4*)&Ssq[(4 * quad + r) * 68 + 4 * m16] = vv;
        }
        if ((n >> 4) == i) {
            #pragma unroll
            for (int c = 0; c < 16; ++c)
                *(float4*)&s[4 * c] = *(const float4*)&Ssq[(n & 15) * 68 + 4 * c];
        }
    }

    // ---- cosine scales (positive; preserve top-k ordering) ----
    const float qs = temp[h] / fmaxf(sqrtf(qnb[n]), 1e-12f);
    #pragma unroll
    for (int c = 0; c < 16; ++c) {
        float4 kv = *(const float4*)&ksb[4 * c];
        s[4*c+0] *= qs * kv.x; s[4*c+1] *= qs * kv.y;
        s[4*c+2] *= qs * kv.z; s[4*c+3] *= qs * kv.w;
    }

    // ---- top-16 threshold via masked v_max3 trees (bit-identical) ----
    float thr = 1e30f;
    for (int it = 0; it < IN_CC; ++it) {
        #define MK(c) ((s[(c)] < thr) ? s[(c)] : -1e30f)
        float w[22];
        #pragma unroll
        for (int g = 0; g < 21; ++g) w[g] = m3(MK(3*g), MK(3*g+1), MK(3*g+2));
        w[21] = MK(63);
        #undef MK
        float y[8];
        #pragma unroll
        for (int g = 0; g < 7; ++g) y[g] = m3(w[3*g], w[3*g+1], w[3*g+2]);
        y[7] = w[21];
        thr = m3(m3(y[0], y[1], y[2]), m3(y[3], y[4], y[5]), fmaxf(y[6], y[7]));
    }

    // ---- mask + rpb + softmax (slot c holds true m = 16*(c&3)+(c>>2)) ----
    const int basen = i1 * 15 + j1;
    float mxp[8];
    #pragma unroll
    for (int c = 0; c < 64; ++c) {
        const int m = 16 * (c & 3) + (c >> 2);
        const int i2 = m >> 3, j2 = m & 7;
        float vv = ((s[c] >= thr) ? s[c] : -100.0f)
                 + rpb[basen + (7 - i2) * 15 + (7 - j2)];
        s[c] = vv;
        if (c < 8) mxp[c] = vv; else mxp[c & 7] = fmaxf(mxp[c & 7], vv);
    }
    const float mx = m3(m3(mxp[0], mxp[1], mxp[2]), m3(mxp[3], mxp[4], mxp[5]),
                        fmaxf(mxp[6], mxp[7]));
    float sum = 0.f;
    #pragma unroll
    for (int c = 0; c < 64; ++c) { float e = __expf(s[c] - mx); s[c] = e; sum += e; }
    const float inv = 1.0f / sum;
    #pragma unroll
    for (int c = 0; c < 64; ++c) s[c] *= inv;

    // ---- PV via MFMA, P staged in two 32-row halves (R overlay) ----
    bf16x8 vb[2][2];
    #pragma unroll
    for (int kh2 = 0; kh2 < 2; ++kh2)
        #pragma unroll
        for (int j2 = 0; j2 < 2; ++j2)
            vb[kh2][j2] = *(const bf16x8*)&Vt[(16 * j2 + m16) * 72 + kh2 * 32 + quad * 8];

    f32x4 o[4][2];
    #pragma unroll
    for (int i = 0; i < 4; ++i)
        #pragma unroll
        for (int j2 = 0; j2 < 2; ++j2)
            o[i][j2] = (f32x4)(0.0f);
    #pragma unroll
    for (int hf = 0; hf < 2; ++hf) {
        if ((n >> 5) == hf) {
            #pragma unroll
            for (int g = 0; g < 8; ++g) {
                uint4 w;
                w.x = pk2t(s[8*g+0], s[8*g+1]); w.y = pk2t(s[8*g+2], s[8*g+3]);
                w.z = pk2t(s[8*g+4], s[8*g+5]); w.w = pk2t(s[8*g+6], s[8*g+7]);
                *(uint4*)&Ph[(n & 31) * 72 + 8 * g] = w;
            }
        }
        #pragma unroll
        for (int ih = 0; ih < 2; ++ih) {
            const int i = 2 * hf + ih;
            #pragma unroll
            for (int kh2 = 0; kh2 < 2; ++kh2) {
                bf16x8 pafr = *(const bf16x8*)&Ph[(16 * ih + m16) * 72 + kh2 * 32 + quad * 8];
                o[i][0] = __builtin_amdgcn_mfma_f32_16x16x32_bf16(pafr, vb[kh2][0], o[i][0], 0, 0, 0);
                o[i][1] = __builtin_amdgcn_mfma_f32_16x16x32_bf16(pafr, vb[kh2][1], o[i][1], 0, 0, 0);
            }
        }
    }
    __syncthreads();   // B3: all waves done with arenas -> AoT may overlay

    // ---- O -> shared AoT tile (bf16, token-major, stride 200) ----
    #pragma unroll
    for (int i = 0; i < 4; ++i) {
        #pragma unroll
        for (int r = 0; r < 4; ++r) {
            const int row = 16 * i + 4 * quad + r;
            AoT[row][h * 32 + m16]      = f2bt(o[i][0][r]);
            AoT[row][h * 32 + 16 + m16] = f2bt(o[i][1][r]);
        }
    }
    __syncthreads();   // B4

    // ---- residual prefetch: AFTER B4, low-pressure region; latency hidden
    //      under the proj GEMM. Lines are L2-warm. ----
    const int r8 = n >> 3, c4 = (n & 7) * 4;
    uint2 rv[4][2];
    #pragma unroll
    for (int i = 0; i < 4; ++i)
        #pragma unroll
        for (int q = 0; q < 2; ++q) {
            const int tok = 16 * i + 8 * q + r8;
            const int tt = wb + ((tok >> 3) << 6) + (tok & 7);
            rv[i][q] = *(const uint2*)(sc_h + (size_t)tt * 192 + h * 32 + c4);
        }

    // ---- proj: wave computes outs [h*32, h*32+32) of its window, K=192 ----
    f32x4 pacc[4][2];
    #pragma unroll
    for (int i = 0; i < 4; ++i)
        #pragma unroll
        for (int j = 0; j < 2; ++j)
            pacc[i][j] = (f32x4)(0.0f);
    const ushort_t* Wb = wpf + (size_t)(h * 2) * 24 * 128 + m16 * 8;
    for (int ks = 0; ks < 192; ks += 32) {
        bf16x8 af[4], wv[2];
        #pragma unroll
        for (int i = 0; i < 4; ++i)
            af[i] = *(const bf16x8*)&AoT[16 * i + m16][quad * 8 + ks];
        #pragma unroll
        for (int j = 0; j < 2; ++j)
            wv[j] = *(const bf16x8*)(Wb + (size_t)(j * 24 + (ks >> 3) + quad) * 128);
        #pragma unroll
        for (int i = 0; i < 4; ++i)
            #pragma unroll
            for (int j = 0; j < 2; ++j)
                pacc[i][j] = __builtin_amdgcn_mfma_f32_16x16x32_bf16(wv[j], af[i], pacc[i][j], 0, 0, 0);
    }

    // ---- per i-group: stage C^T (+bias) into Cwi[16][36]; store x2 with
    //      full 128-B-granule coverage per instruction. ----
    const float4 bj0 = *(const float4*)&proj_b[h * 32 + quad * 4];
    const float4 bj1 = *(const float4*)&proj_b[h * 32 + 16 + quad * 4];
    #pragma unroll
    for (int i = 0; i < 4; ++i) {
        f32x4 v0 = pacc[i][0], v1 = pacc[i][1];
        v0[0] += bj0.x; v0[1] += bj0.y; v0[2] += bj0.z; v0[3] += bj0.w;
        v1[0] += bj1.x; v1[1] += bj1.y; v1[2] += bj1.z; v1[3] += bj1.w;
        *(f32x4*)&Cwi[m16 * 36 + quad * 4]      = v0;
        *(f32x4*)&Cwi[m16 * 36 + 16 + quad * 4] = v1;
        #pragma unroll
        for (int q = 0; q < 2; ++q) {
            const int row = 8 * q + r8;
            const int tok = 16 * i + row;
            const int tt = wb + ((tok >> 3) << 6) + (tok & 7);
            float4 vv = *(const float4*)&Cwi[row * 36 + c4];
            const uint2 rr = rv[i][q];
            vv.x += b2f((ushort_t)(rr.x & 0xffffu));
            vv.y += b2f((ushort_t)(rr.x >> 16));
            vv.z += b2f((ushort_t)(rr.y & 0xffffu));
            vv.w += b2f((ushort_t)(rr.y >> 16));
            *(float4*)&x2[(size_t)tt * DIM + h * 32 + c4] = vv;
        }
    }
}

// ---------------------------------------------------------------------------
// FUSED MLP v2 (round-8 validated): 128 tokens/block, 12 waves, grid 256.
// Native bf16 converts (f2b/pk2) — mlp is far from the register cliff.
__global__ __launch_bounds__(768, 3) void mlp_fused(
    const float* __restrict__ x2, const ushort_t* __restrict__ w1f,
    const ushort_t* __restrict__ w2f, const float* __restrict__ fc1_b,
    const float* __restrict__ fc2_b, const float* __restrict__ g2,
    const float* __restrict__ b2, float* __restrict__ outp)
{
    __shared__ __align__(16) char smem[103936];
    ushort_t (*h_h)[200] = (ushort_t(*)[200])smem;             // [128][200]
    ushort_t (*a1c)[200] = (ushort_t(*)[200])(smem + 51200);   // [128][200]
    float* gs = (float*)(smem + 102400);
    float* bs = gs + 192;

    const int tid  = threadIdx.x;
    const int wave = tid >> 6, lane = tid & 63;
    const int m16 = lane & 15, quad = lane >> 4;
    const int half = wave / 6, ow = wave - 6 * half;   // token-half, out-group
    const int t0  = blockIdx.x * 128;
    const int b   = t0 >> 12;
    const int hw0 = t0 & 4095;

    if (tid < 192) { gs[tid] = g2[tid]; bs[tid] = b2[tid]; }
    __syncthreads();
    if (tid < 512) {
        const int tok = tid >> 2, p = tid & 3;
        const float* rp = x2 + (size_t)(t0 + tok) * DIM + p * 48;
        float xv[48];
        #pragma unroll
        for (int c4 = 0; c4 < 12; ++c4)
            *(float4*)&xv[c4 * 4] = *(const float4*)(rp + c4 * 4);
        float sum = 0.f;
        #pragma unroll
        for (int c = 0; c < 48; ++c) sum += xv[c];
        sum += __shfl_xor(sum, 1);
        sum += __shfl_xor(sum, 2);
        const float m = sum * (1.0f / 192.0f);
        float ss = 0.f;
        #pragma unroll
        for (int c = 0; c < 48; ++c) { float d = xv[c] - m; ss += d * d; }
        ss += __shfl_xor(ss, 1);
        ss += __shfl_xor(ss, 2);
        const float rs = 1.0f / sqrtf(ss * (1.0f / 192.0f) + 1e-5f);
        ushort_t* hp = &h_h[tok][p * 48];
        #pragma unroll
        for (int c2 = 0; c2 < 24; ++c2) {
            float v0 = (xv[2*c2]   - m) * rs * gs[p * 48 + 2*c2]   + bs[p * 48 + 2*c2];
            float v1 = (xv[2*c2+1] - m) * rs * gs[p * 48 + 2*c2+1] + bs[p * 48 + 2*c2+1];
            *(unsigned*)(hp + 2 * c2) = pk2(v0, v1);
        }
    }
    __syncthreads();

    f32x4 acc2[4][2];
    #pragma unroll
    for (int i = 0; i < 4; ++i)
        #pragma unroll
        for (int j = 0; j < 2; ++j)
            acc2[i][j] = (f32x4)(0.0f);

    for (int c = 0; c < 4; ++c) {                 // 4 chunks of 192 fc1-outs
        f32x4 acc1[4][2];
        #pragma unroll
        for (int i = 0; i < 4; ++i)
            #pragma unroll
            for (int j = 0; j < 2; ++j)
                acc1[i][j] = (f32x4)(0.0f);
        const ushort_t* Wb1 = w1f + (size_t)(c * 12 + ow * 2) * 3072 + m16 * 8;
        for (int ks = 0; ks < 192; ks += 32) {
            bf16x8 af[4], wv[2];
            #pragma unroll
            for (int i = 0; i < 4; ++i)
                af[i] = *(const bf16x8*)&h_h[half * 64 + 16 * i + m16][quad * 8 + ks];
            #pragma unroll
            for (int j = 0; j < 2; ++j)
                wv[j] = *(const bf16x8*)(Wb1 + (size_t)(j * 24 + (ks >> 3) + quad) * 128);
            #pragma unroll
            for (int i = 0; i < 4; ++i)
                #pragma unroll
                for (int j = 0; j < 2; ++j)
                    acc1[i][j] = __builtin_amdgcn_mfma_f32_16x16x32_bf16(wv[j], af[i], acc1[i][j], 0, 0, 0);
        }
        #pragma unroll
        for (int j = 0; j < 2; ++j) {
            const int o = c * 192 + ow * 32 + 16 * j + quad * 4;
            const float4 bv = *(const float4*)&fc1_b[o];
            #pragma unroll
            for (int i = 0; i < 4; ++i) {
                f32x4 v = acc1[i][j];
                v[0] += bv.x; v[1] += bv.y; v[2] += bv.z; v[3] += bv.w;
                #pragma unroll
                for (int r = 0; r < 4; ++r) {
                    float xg = v[r];
                    float e1 = __expf(xg * (1.5957691f + 0.0713548f * xg * xg)) + 1.0f;
                    v[r] = xg - xg * __builtin_amdgcn_rcpf(e1);
                }
                uint2 pkd;
                pkd.x = pk2(v[0], v[1]); pkd.y = pk2(v[2], v[3]);
                *(uint2*)&a1c[half * 64 + 16 * i + m16][ow * 32 + 16 * j + quad * 4] = pkd;
            }
        }
        __syncthreads();
        const ushort_t* Wb2 = w2f + (size_t)(ow * 2) * 12288 + m16 * 8;
        for (int ks = 0; ks < 192; ks += 32) {
            bf16x8 af2[4], wv2[2];
            #pragma unroll
            for (int i = 0; i < 4; ++i)
                af2[i] = *(const bf16x8*)&a1c[half * 64 + 16 * i + m16][quad * 8 + ks];
            #pragma unroll
            for (int j = 0; j < 2; ++j)
                wv2[j] = *(const bf16x8*)(Wb2 + (size_t)(j * 96 + c * 24 + (ks >> 3) + quad) * 128);
            #pragma unroll
            for (int i = 0; i < 4; ++i)
                #pragma unroll
                for (int j = 0; j < 2; ++j)
                    acc2[i][j] = __builtin_amdgcn_mfma_f32_16x16x32_bf16(wv2[j], af2[i], acc2[i][j], 0, 0, 0);
        }
        __syncthreads();
    }

    // ---- epilogue: stage [32 tok][32 outs] per pass, write NCHW with
    //      full 128-B-granule runs (64-token-consecutive per channel). ----
    float* Cw = (float*)(smem + wave * 4608);      // [32][36] f32, overlay
    float4 b2j[2];
    #pragma unroll
    for (int j = 0; j < 2; ++j)
        b2j[j] = *(const float4*)&fc2_b[ow * 32 + 16 * j + quad * 4];
    #pragma unroll
    for (int p = 0; p < 2; ++p) {
        #pragma unroll
        for (int ih = 0; ih < 2; ++ih) {
            const int i = 2 * p + ih;
            #pragma unroll
            for (int j = 0; j < 2; ++j) {
                f32x4 v = acc2[i][j];
                v[0] += b2j[j].x; v[1] += b2j[j].y; v[2] += b2j[j].z; v[3] += b2j[j].w;
                *(f32x4*)&Cw[(ih * 16 + m16) * 36 + 16 * j + quad * 4] = v;
            }
        }
        #pragma unroll
        for (int q = 0; q < 4; ++q) {
            const int idx = q * 64 + lane;
            const int cc = idx >> 3, t4 = (idx & 7) * 4;
            const int o  = ow * 32 + cc;
            const int tb = t0 + half * 64 + p * 32 + t4;
            float4 vv;
            vv.x = Cw[(t4 + 0) * 36 + cc] + x2[(size_t)(tb + 0) * DIM + o];
            vv.y = Cw[(t4 + 1) * 36 + cc] + x2[(size_t)(tb + 1) * DIM + o];
            vv.z = Cw[(t4 + 2) * 36 + cc] + x2[(size_t)(tb + 2) * DIM + o];
            vv.w = Cw[(t4 + 3) * 36 + cc] + x2[(size_t)(tb + 3) * DIM + o];
            *(float4*)&outp[(size_t)b * (DIM * 4096) + (size_t)o * 4096
                            + hw0 + half * 64 + p * 32 + t4] = vv;
        }
    }
}

// ---------------------------------------------------------------------------
extern "C" void kernel_launch(void* const* d_in, const int* in_sizes, int n_in,
                              void* d_out, int out_size, void* d_ws, size_t ws_size,
                              hipStream_t stream)
{
    const float* x        = (const float*)d_in[0];
    const float* norm1_g  = (const float*)d_in[1];
    const float* norm1_b  = (const float*)d_in[2];
    const float* qkv_w    = (const float*)d_in[3];
    const float* qkv_b    = (const float*)d_in[4];
    const float* proj_w   = (const float*)d_in[5];
    const float* proj_b   = (const float*)d_in[6];
    const float* rpbt     = (const float*)d_in[7];
    const float* temp     = (const float*)d_in[8];
    const float* norm2_g  = (const float*)d_in[9];
    const float* norm2_b  = (const float*)d_in[10];
    const float* fc1_w    = (const float*)d_in[11];
    const float* fc1_b    = (const float*)d_in[12];
    const float* fc2_w    = (const float*)d_in[13];
    const float* fc2_b    = (const float*)d_in[14];
    float* out = (float*)d_out;

    // ws layout (bytes):
    //   [0,        12582912)  shortcut bf16 (LN1 out)
    //   [12582912, 37748736)  x2 f32
    //   [125829120,...)       weights bf16 (fragment order; qkv Q/K permuted)
    char* wsb = (char*)d_ws;
    ushort_t* shortcut_h = (ushort_t*)wsb;
    float*    x2         = (float*)(wsb + 12582912);
    ushort_t* wq  = (ushort_t*)(wsb + 125829120);      // 576x192 = 110592
    ushort_t* wp  = wq + 110592;                       // 192x192 = 36864
    ushort_t* w1  = wp + 36864;                        // 768x192 = 147456
    ushort_t* w2  = w1 + 147456;                       // 192x768 = 147456

    // 0+1. merged weight conversion (432 blocks) + LN1 transpose (512 blocks)
    hipLaunchKernelGGL(prep_kernel, dim3(432 + TTOT / 64), dim3(256), 0, stream,
                       qkv_w, proj_w, fc1_w, fc2_w, wq, wp, w1, w2,
                       x, norm1_g, norm1_b, shortcut_h);
    // 2. fused qkv + attention + proj + residual -> x2 (2 windows/block)
    hipLaunchKernelGGL(attn_fused, dim3(NWIN / 2), dim3(768), 0, stream,
                       shortcut_h, wq, qkv_b, rpbt, temp, wp, proj_b, x2);
    // 3. fused LN2 + fc1 + GELU + fc2 + residual + NCHW transpose
    hipLaunchKernelGGL(mlp_fused, dim3(TTOT / 128), dim3(768), 0, stream,
                       x2, w1, w2, fc1_b, fc2_b, norm2_g, norm2_b, out);
}

// Round 13
// 188.517 us; speedup vs baseline: 1.0108x; 1.0018x over previous
//
#include <hip/hip_runtime.h>
#include <hip/hip_bf16.h>
#include <math.h>

// Problem constants
#define DIM     192
#define HEADS   6
#define HEAD_DIM 32
#define NTOK    64          // tokens per window
#define IN_CC   16
#define TTOT    32768       // 8 * 64 * 64 tokens
#define NWIN    512

using bf16x8 = __attribute__((ext_vector_type(8))) short;
using f32x4  = __attribute__((ext_vector_type(4))) float;
typedef unsigned short ushort_t;

#define PRIO_HI() __builtin_amdgcn_s_setprio(1)
#define PRIO_LO() __builtin_amdgcn_s_setprio(0)

// ---------------------------------------------------------------------------
// TWO bf16 convert families (same RNE result, different codegen):
//  - f2bt/pk2t: bit-twiddle, short live ranges (attn at the 168-reg cap;
//    native casts there re-triggered ~6 MB scratch spill — round 7).
//  - f2b/pk2: native casts (prep / mlp — off the register cliff).
__device__ __forceinline__ ushort_t f2bt(float f) {
    unsigned u = __float_as_uint(f);
    u += 0x7fffu + ((u >> 16) & 1u);
    return (ushort_t)(u >> 16);
}
__device__ __forceinline__ unsigned pk2t(float a, float b) {
    return (unsigned)f2bt(a) | ((unsigned)f2bt(b) << 16);
}
__device__ __forceinline__ ushort_t f2b(float f) {
    __bf16 h = (__bf16)f;
    ushort_t u;
    __builtin_memcpy(&u, &h, 2);
    return u;
}
__device__ __forceinline__ unsigned pk2(float a, float b) {
    return (unsigned)f2b(a) | ((unsigned)f2b(b) << 16);
}
__device__ __forceinline__ float b2f(ushort_t u) {
    return __uint_as_float(((unsigned)u) << 16);
}
__device__ __forceinline__ float m3(float a, float b, float c) {
    return fmaxf(fmaxf(a, b), c);     // clang fuses to v_max3_f32
}

// ---------------------------------------------------------------------------
// PREP kernel: weight fp32->bf16 fragment-order conversion (432 blocks)
// MERGED with LN1+transpose (512 blocks).
// cvt part: W (NxK row-major) -> W' where element (o,k) lives at
//   frag = (o/16)*(K/8) + (k/8);  W'[frag*128 + (o%16)*8 + (k%8)]
// qkv weight ONLY: Q and K parts (rows [0,384)) get a within-head output-row
// permutation so the qkv GEMM's C-fragment IS the QK^T MFMA A/B fragment
// (slot s=16j+4q+r holds natural channel c=8q+4j+r). QK^T is invariant under
// a common channel permutation of q and k.
__global__ __launch_bounds__(256) void prep_kernel(
    const float* __restrict__ s0, const float* __restrict__ s1,
    const float* __restrict__ s2, const float* __restrict__ s3,
    ushort_t* __restrict__ d0, ushort_t* __restrict__ d1,
    ushort_t* __restrict__ d2, ushort_t* __restrict__ d3,
    const float* __restrict__ x, const float* __restrict__ g,
    const float* __restrict__ bb, ushort_t* __restrict__ outh)
{
    __shared__ float xs[64][193];
    __shared__ float mu_s[64], rs_s[64];
    __shared__ float gs[192], bs[192];
    const int bid = blockIdx.x;
    const int tid = threadIdx.x;

    if (bid < 432) {
        // ---------------- weight conversion ----------------
        const float* src; ushort_t* dst; int off, K; bool perm = false;
        if (bid < 108)      { src = s0; dst = d0; off = bid;       K = 192; perm = true; }
        else if (bid < 144) { src = s1; dst = d1; off = bid - 108; K = 192; }
        else if (bid < 288) { src = s2; dst = d2; off = bid - 144; K = 192; }
        else                { src = s3; dst = d3; off = bid - 288; K = 768; }
        const int K8 = K >> 3;
        const int d  = (off * 256 + tid) * 4;
        const int frag = d >> 7, win = d & 127;
        const int m16w = win >> 3, k7 = win & 7;
        const int oblk = frag / K8, kblk = frag - oblk * K8;
        const int o = oblk * 16 + m16w, k = kblk * 8 + k7;
        int so = o;
        if (perm && o < 384) {
            const int s = o & 31;                       // slot within head block
            const int c = (((s >> 2) & 3) << 3) | (((s >> 4) & 1) << 2) | (s & 3);
            so = (o & ~31) | c;                         // natural channel row
        }
        float4 v = *(const float4*)(src + (size_t)so * K + k);
        ushort4 ov;
        ov.x = f2b(v.x); ov.y = f2b(v.y); ov.z = f2b(v.z); ov.w = f2b(v.w);
        *(ushort4*)(dst + d) = ov;
        return;
    }

    // ---------------- LN1 + (B,C,H,W)->(T,C) transpose, bf16 out ----------------
    const int t0  = (bid - 432) * 64;
    const int b   = t0 >> 12;
    const int hw0 = t0 & 4095;
    if (tid < 192) { gs[tid] = g[tid]; bs[tid] = bb[tid]; }
    const int tok = tid & 63, qq = tid >> 6;
    const float* xb = x + (size_t)b * (DIM * 4096) + hw0 + tok;
    #pragma unroll
    for (int it = 0; it < 48; ++it) {
        int c = it * 4 + qq;
        xs[tok][c] = xb[(size_t)c * 4096];
    }
    __syncthreads();
    const int tok2 = tid >> 2, p = tid & 3;
    float sum = 0.f;
    #pragma unroll
    for (int c = 0; c < 48; ++c) sum += xs[tok2][p * 48 + c];
    sum += __shfl_xor(sum, 1);
    sum += __shfl_xor(sum, 2);
    const float m = sum * (1.0f / 192.0f);
    float ss = 0.f;
    #pragma unroll
    for (int c = 0; c < 48; ++c) { float d = xs[tok2][p * 48 + c] - m; ss += d * d; }
    ss += __shfl_xor(ss, 1);
    ss += __shfl_xor(ss, 2);
    if (p == 0) {
        mu_s[tok2] = m;
        rs_s[tok2] = 1.0f / sqrtf(ss * (1.0f / 192.0f) + 1e-5f);
    }
    __syncthreads();
    ushort_t* obh = outh + (size_t)t0 * DIM;
    #pragma unroll
    for (int it = 0; it < 48; ++it) {
        int idx = it * 256 + tid;
        int tk = idx / 192, c = idx % 192;
        obh[idx] = f2b((xs[tk][c] - mu_s[tk]) * rs_s[tk] * gs[c] + bs[c]);
    }
}

// ---------------------------------------------------------------------------
// MEGA-FUSED attention — round-8 validated structure + s_setprio around MFMA
// clusters (T5; scheduling-only, zero numerics impact).
__global__ __launch_bounds__(768, 3) void attn_fused(
    const ushort_t* __restrict__ sc_h, const ushort_t* __restrict__ wqf,
    const float* __restrict__ qkv_b, const float* __restrict__ rpb_table,
    const float* __restrict__ temp, const ushort_t* __restrict__ wpf,
    const float* __restrict__ proj_b, float* __restrict__ x2)
{
    __shared__ __align__(16) char smem[127680];
    const int tid  = threadIdx.x;
    const int wave = tid >> 6, n = tid & 63;

    char* Rb = smem + wave * 4608;
    float*    Ssq = (float*)Rb;                  // [16][68] f32 transpose qtr
    ushort_t* Ph  = (ushort_t*)Rb;               // [32][72] bf16 P half (ovl)
    char* Ab = smem + 55296 + wave * 5120;
    ushort_t* Vt  = (ushort_t*)Ab;               // [32][72] V^T slot-permuted
    float*    ksb = (float*)(Ab + 4608);         // [64] slot-ordered 1/||k||
    float*    qnb = (float*)(Ab + 4864);         // [64] ssq of q per token
    float*    rpb = (float*)(smem + 116736) + wave * 228;

    const int wloc = (wave >= 6) ? 1 : 0;        // window within block
    const int h    = wave - 6 * wloc;            // head
    ushort_t* tile = (ushort_t*)(smem + wloc * 25600);       // [64][200] bf16
    ushort_t (*AoT)[200] = (ushort_t(*)[200])(smem + wloc * 25600);
    float* Cwi = (float*)(smem + 55296 + wave * 2304);       // [16][36] f32

    const int win = blockIdx.x * 2 + wloc;
    const int b   = win >> 6;
    const int wh  = (win >> 3) & 7, ww = win & 7;
    const int wb  = b * 4096 + wh * 512 + ww * 8;
    const int i1  = n >> 3, j1 = n & 7;
    const int m16 = n & 15, quad = n >> 4;

    for (int r = n; r < 225; r += 64) rpb[r] = rpb_table[r * 6 + h];

    // ---- phase 0: stage this window's shortcut tile into LDS (once) ----
    #pragma unroll
    for (int l = 0; l < 4; ++l) {
        const int g = h * 256 + l * 64 + n;
        const int t = (g * 2731) >> 16;          // g / 24
        const int r = g - t * 24;
        const int tt = wb + ((t >> 3) << 6) + (t & 7);
        uint4 v = *(const uint4*)(sc_h + (size_t)tt * 192 + r * 8);
        *(uint4*)(tile + t * 200 + r * 8) = v;
    }
    __syncthreads();                              // B1: tile ready

    // ---- phase 1a: q & k GEMMs sharing af fragments (all LDS reads) ----
    const ushort_t* tb = tile + m16 * 200 + quad * 8;
    f32x4 pq[4][2], pk[4][2];
    #pragma unroll
    for (int i = 0; i < 4; ++i)
        #pragma unroll
        for (int j = 0; j < 2; ++j) { pq[i][j] = (f32x4)(0.0f); pk[i][j] = (f32x4)(0.0f); }
    {
        const ushort_t* WbQ = wqf + (size_t)(2 * h) * 3072 + m16 * 8;
        const ushort_t* WbK = wqf + (size_t)(12 + 2 * h) * 3072 + m16 * 8;
        for (int ks = 0; ks < 192; ks += 32) {
            bf16x8 af[4], wq2[2], wk2[2];
            #pragma unroll
            for (int i = 0; i < 4; ++i)
                af[i] = *(const bf16x8*)(tb + i * 3200 + ks);
            #pragma unroll
            for (int j = 0; j < 2; ++j) {
                wq2[j] = *(const bf16x8*)(WbQ + (size_t)(j * 24 + (ks >> 3) + quad) * 128);
                wk2[j] = *(const bf16x8*)(WbK + (size_t)(j * 24 + (ks >> 3) + quad) * 128);
            }
            PRIO_HI();
            #pragma unroll
            for (int i = 0; i < 4; ++i)
                #pragma unroll
                for (int j = 0; j < 2; ++j) {
                    pq[i][j] = __builtin_amdgcn_mfma_f32_16x16x32_bf16(wq2[j], af[i], pq[i][j], 0, 0, 0);
                    pk[i][j] = __builtin_amdgcn_mfma_f32_16x16x32_bf16(wk2[j], af[i], pk[i][j], 0, 0, 0);
                }
            PRIO_LO();
        }
    }
    // q/k epilogue: bias, ssq, pack to QK^T fragments (permuted slots)
    bf16x8 qA[4], kB[4];
    #pragma unroll
    for (int part = 0; part < 2; ++part) {
        const int o0 = part * 192 + h * 32;
        const float4 bv0 = *(const float4*)&qkv_b[o0 + 8 * quad];
        const float4 bv1 = *(const float4*)&qkv_b[o0 + 8 * quad + 4];
        float ssq[4];
        #pragma unroll
        for (int i = 0; i < 4; ++i) {
            f32x4 v0 = part ? pk[i][0] : pq[i][0];
            f32x4 v1 = part ? pk[i][1] : pq[i][1];
            v0[0] += bv0.x; v0[1] += bv0.y; v0[2] += bv0.z; v0[3] += bv0.w;
            v1[0] += bv1.x; v1[1] += bv1.y; v1[2] += bv1.z; v1[3] += bv1.w;
            float sq = 0.f;
            #pragma unroll
            for (int r = 0; r < 4; ++r) sq += v0[r] * v0[r] + v1[r] * v1[r];
            ssq[i] = sq;
            bf16x8 fr;
            fr[0] = (short)f2bt(v0[0]); fr[1] = (short)f2bt(v0[1]);
            fr[2] = (short)f2bt(v0[2]); fr[3] = (short)f2bt(v0[3]);
            fr[4] = (short)f2bt(v1[0]); fr[5] = (short)f2bt(v1[1]);
            fr[6] = (short)f2bt(v1[2]); fr[7] = (short)f2bt(v1[3]);
            if (part == 0) qA[i] = fr; else kB[i] = fr;
        }
        #pragma unroll
        for (int i = 0; i < 4; ++i) {
            ssq[i] += __shfl_xor(ssq[i], 16);
            ssq[i] += __shfl_xor(ssq[i], 32);
        }
        if (quad == 0) {
            #pragma unroll
            for (int i = 0; i < 4; ++i) {
                if (part == 0) qnb[16 * i + m16] = ssq[i];
                else           ksb[4 * m16 + i]  = 1.0f / fmaxf(sqrtf(ssq[i]), 1e-12f);
            }
        }
    }

    // ---- phase 2: QK^T, register-to-register ----
    f32x4 acc[4][4];
    PRIO_HI();
    #pragma unroll
    for (int i = 0; i < 4; ++i)
        #pragma unroll
        for (int j = 0; j < 4; ++j)
            acc[i][j] = __builtin_amdgcn_mfma_f32_16x16x32_bf16(qA[i], kB[j], (f32x4)(0.0f), 0, 0, 0);
    PRIO_LO();

    // ---- phase 1b: v GEMM (af re-read from LDS) ----
    {
        f32x4 pv[4][2];
        #pragma unroll
        for (int i = 0; i < 4; ++i)
            #pragma unroll
            for (int j = 0; j < 2; ++j) pv[i][j] = (f32x4)(0.0f);
        const ushort_t* WbV = wqf + (size_t)(24 + 2 * h) * 3072 + m16 * 8;
        for (int ks = 0; ks < 192; ks += 32) {
            bf16x8 af[4], wv2[2];
            #pragma unroll
            for (int i = 0; i < 4; ++i)
                af[i] = *(const bf16x8*)(tb + i * 3200 + ks);
            #pragma unroll
            for (int j = 0; j < 2; ++j)
                wv2[j] = *(const bf16x8*)(WbV + (size_t)(j * 24 + (ks >> 3) + quad) * 128);
            PRIO_HI();
            #pragma unroll
            for (int i = 0; i < 4; ++i)
                #pragma unroll
                for (int j = 0; j < 2; ++j)
                    pv[i][j] = __builtin_amdgcn_mfma_f32_16x16x32_bf16(wv2[j], af[i], pv[i][j], 0, 0, 0);
            PRIO_LO();
        }
        const int o0 = 384 + h * 32;
        const float4 bv0 = *(const float4*)&qkv_b[o0 + quad * 4];
        const float4 bv1 = *(const float4*)&qkv_b[o0 + 16 + quad * 4];
        #pragma unroll
        for (int i = 0; i < 4; ++i) {
            f32x4 v0 = pv[i][0], v1 = pv[i][1];
            v0[0] += bv0.x; v0[1] += bv0.y; v0[2] += bv0.z; v0[3] += bv0.w;
            v1[0] += bv1.x; v1[1] += bv1.y; v1[2] += bv1.z; v1[3] += bv1.w;
            #pragma unroll
            for (int r = 0; r < 4; ++r) {
                Vt[(quad * 4 + r) * 72 + 4 * m16 + i]      = f2bt(v0[r]);
                Vt[(16 + quad * 4 + r) * 72 + 4 * m16 + i] = f2bt(v1[r]);
            }
        }
    }

    __syncthreads();                              // B2: tiles dead, R usable

    // ---- transpose S via 16-row quarter buffer (wave-local) ----
    float s[64];
    #pragma unroll
    for (int i = 0; i < 4; ++i) {
        #pragma unroll
        for (int r = 0; r < 4; ++r) {
            f32x4 vv = { acc[i][0][r], acc[i][1][r], acc[i][2][r], acc[i][3][r] };
            *(f32x4*)&Ssq[(4 * quad + r) * 68 + 4 * m16] = vv;
        }
        if ((n >> 4) == i) {
            #pragma unroll
            for (int c = 0; c < 16; ++c)
                *(float4*)&s[4 * c] = *(const float4*)&Ssq[(n & 15) * 68 + 4 * c];
        }
    }

    // ---- cosine scales (positive; preserve top-k ordering) ----
    const float qs = temp[h] / fmaxf(sqrtf(qnb[n]), 1e-12f);
    #pragma unroll
    for (int c = 0; c < 16; ++c) {
        float4 kv = *(const float4*)&ksb[4 * c];
        s[4*c+0] *= qs * kv.x; s[4*c+1] *= qs * kv.y;
        s[4*c+2] *= qs * kv.z; s[4*c+3] *= qs * kv.w;
    }

    // ---- top-16 threshold via masked v_max3 trees (bit-identical) ----
    float thr = 1e30f;
    for (int it = 0; it < IN_CC; ++it) {
        #define MK(c) ((s[(c)] < thr) ? s[(c)] : -1e30f)
        float w[22];
        #pragma unroll
        for (int g = 0; g < 21; ++g) w[g] = m3(MK(3*g), MK(3*g+1), MK(3*g+2));
        w[21] = MK(63);
        #undef MK
        float y[8];
        #pragma unroll
        for (int g = 0; g < 7; ++g) y[g] = m3(w[3*g], w[3*g+1], w[3*g+2]);
        y[7] = w[21];
        thr = m3(m3(y[0], y[1], y[2]), m3(y[3], y[4], y[5]), fmaxf(y[6], y[7]));
    }

    // ---- mask + rpb + softmax (slot c holds true m = 16*(c&3)+(c>>2)) ----
    const int basen = i1 * 15 + j1;
    float mxp[8];
    #pragma unroll
    for (int c = 0; c < 64; ++c) {
        const int m = 16 * (c & 3) + (c >> 2);
        const int i2 = m >> 3, j2 = m & 7;
        float vv = ((s[c] >= thr) ? s[c] : -100.0f)
                 + rpb[basen + (7 - i2) * 15 + (7 - j2)];
        s[c] = vv;
        if (c < 8) mxp[c] = vv; else mxp[c & 7] = fmaxf(mxp[c & 7], vv);
    }
    const float mx = m3(m3(mxp[0], mxp[1], mxp[2]), m3(mxp[3], mxp[4], mxp[5]),
                        fmaxf(mxp[6], mxp[7]));
    float sum = 0.f;
    #pragma unroll
    for (int c = 0; c < 64; ++c) { float e = __expf(s[c] - mx); s[c] = e; sum += e; }
    const float inv = 1.0f / sum;
    #pragma unroll
    for (int c = 0; c < 64; ++c) s[c] *= inv;

    // ---- PV via MFMA, P staged in two 32-row halves (R overlay) ----
    bf16x8 vb[2][2];
    #pragma unroll
    for (int kh2 = 0; kh2 < 2; ++kh2)
        #pragma unroll
        for (int j2 = 0; j2 < 2; ++j2)
            vb[kh2][j2] = *(const bf16x8*)&Vt[(16 * j2 + m16) * 72 + kh2 * 32 + quad * 8];

    f32x4 o[4][2];
    #pragma unroll
    for (int i = 0; i < 4; ++i)
        #pragma unroll
        for (int j2 = 0; j2 < 2; ++j2)
            o[i][j2] = (f32x4)(0.0f);
    #pragma unroll
    for (int hf = 0; hf < 2; ++hf) {
        if ((n >> 5) == hf) {
            #pragma unroll
            for (int g = 0; g < 8; ++g) {
                uint4 w;
                w.x = pk2t(s[8*g+0], s[8*g+1]); w.y = pk2t(s[8*g+2], s[8*g+3]);
                w.z = pk2t(s[8*g+4], s[8*g+5]); w.w = pk2t(s[8*g+6], s[8*g+7]);
                *(uint4*)&Ph[(n & 31) * 72 + 8 * g] = w;
            }
        }
        #pragma unroll
        for (int ih = 0; ih < 2; ++ih) {
            const int i = 2 * hf + ih;
            #pragma unroll
            for (int kh2 = 0; kh2 < 2; ++kh2) {
                bf16x8 pafr = *(const bf16x8*)&Ph[(16 * ih + m16) * 72 + kh2 * 32 + quad * 8];
                PRIO_HI();
                o[i][0] = __builtin_amdgcn_mfma_f32_16x16x32_bf16(pafr, vb[kh2][0], o[i][0], 0, 0, 0);
                o[i][1] = __builtin_amdgcn_mfma_f32_16x16x32_bf16(pafr, vb[kh2][1], o[i][1], 0, 0, 0);
                PRIO_LO();
            }
        }
    }
    __syncthreads();   // B3: all waves done with arenas -> AoT may overlay

    // ---- O -> shared AoT tile (bf16, token-major, stride 200) ----
    #pragma unroll
    for (int i = 0; i < 4; ++i) {
        #pragma unroll
        for (int r = 0; r < 4; ++r) {
            const int row = 16 * i + 4 * quad + r;
            AoT[row][h * 32 + m16]      = f2bt(o[i][0][r]);
            AoT[row][h * 32 + 16 + m16] = f2bt(o[i][1][r]);
        }
    }
    __syncthreads();   // B4

    // ---- residual prefetch: AFTER B4, low-pressure region; latency hidden
    //      under the proj GEMM. Lines are L2-warm. ----
    const int r8 = n >> 3, c4 = (n & 7) * 4;
    uint2 rv[4][2];
    #pragma unroll
    for (int i = 0; i < 4; ++i)
        #pragma unroll
        for (int q = 0; q < 2; ++q) {
            const int tok = 16 * i + 8 * q + r8;
            const int tt = wb + ((tok >> 3) << 6) + (tok & 7);
            rv[i][q] = *(const uint2*)&sc_h[(size_t)tt * 192 + h * 32 + c4];
        }

    // ---- proj: wave computes outs [h*32, h*32+32) of its window, K=192 ----
    f32x4 pacc[4][2];
    #pragma unroll
    for (int i = 0; i < 4; ++i)
        #pragma unroll
        for (int j = 0; j < 2; ++j)
            pacc[i][j] = (f32x4)(0.0f);
    const ushort_t* Wb = wpf + (size_t)(h * 2) * 24 * 128 + m16 * 8;
    for (int ks = 0; ks < 192; ks += 32) {
        bf16x8 af[4], wv[2];
        #pragma unroll
        for (int i = 0; i < 4; ++i)
            af[i] = *(const bf16x8*)&AoT[16 * i + m16][quad * 8 + ks];
        #pragma unroll
        for (int j = 0; j < 2; ++j)
            wv[j] = *(const bf16x8*)(Wb + (size_t)(j * 24 + (ks >> 3) + quad) * 128);
        PRIO_HI();
        #pragma unroll
        for (int i = 0; i < 4; ++i)
            #pragma unroll
            for (int j = 0; j < 2; ++j)
                pacc[i][j] = __builtin_amdgcn_mfma_f32_16x16x32_bf16(wv[j], af[i], pacc[i][j], 0, 0, 0);
        PRIO_LO();
    }

    // ---- per i-group: stage C^T (+bias) into Cwi[16][36]; store x2 with
    //      full 128-B-granule coverage per instruction. ----
    const float4 bj0 = *(const float4*)&proj_b[h * 32 + quad * 4];
    const float4 bj1 = *(const float4*)&proj_b[h * 32 + 16 + quad * 4];
    #pragma unroll
    for (int i = 0; i < 4; ++i) {
        f32x4 v0 = pacc[i][0], v1 = pacc[i][1];
        v0[0] += bj0.x; v0[1] += bj0.y; v0[2] += bj0.z; v0[3] += bj0.w;
        v1[0] += bj1.x; v1[1] += bj1.y; v1[2] += bj1.z; v1[3] += bj1.w;
        *(f32x4*)&Cwi[m16 * 36 + quad * 4]      = v0;
        *(f32x4*)&Cwi[m16 * 36 + 16 + quad * 4] = v1;
        #pragma unroll
        for (int q = 0; q < 2; ++q) {
            const int row = 8 * q + r8;
            const int tok = 16 * i + row;
            const int tt = wb + ((tok >> 3) << 6) + (tok & 7);
            float4 vv = *(const float4*)&Cwi[row * 36 + c4];
            const uint2 rr = rv[i][q];
            vv.x += b2f((ushort_t)(rr.x & 0xffffu));
            vv.y += b2f((ushort_t)(rr.x >> 16));
            vv.z += b2f((ushort_t)(rr.y & 0xffffu));
            vv.w += b2f((ushort_t)(rr.y >> 16));
            *(float4*)&x2[(size_t)tt * DIM + h * 32 + c4] = vv;
        }
    }
}

// ---------------------------------------------------------------------------
// FUSED MLP v2 (round-8 validated) + setprio around MFMA clusters.
__global__ __launch_bounds__(768, 3) void mlp_fused(
    const float* __restrict__ x2, const ushort_t* __restrict__ w1f,
    const ushort_t* __restrict__ w2f, const float* __restrict__ fc1_b,
    const float* __restrict__ fc2_b, const float* __restrict__ g2,
    const float* __restrict__ b2, float* __restrict__ outp)
{
    __shared__ __align__(16) char smem[103936];
    ushort_t (*h_h)[200] = (ushort_t(*)[200])smem;             // [128][200]
    ushort_t (*a1c)[200] = (ushort_t(*)[200])(smem + 51200);   // [128][200]
    float* gs = (float*)(smem + 102400);
    float* bs = gs + 192;

    const int tid  = threadIdx.x;
    const int wave = tid >> 6, lane = tid & 63;
    const int m16 = lane & 15, quad = lane >> 4;
    const int half = wave / 6, ow = wave - 6 * half;   // token-half, out-group
    const int t0  = blockIdx.x * 128;
    const int b   = t0 >> 12;
    const int hw0 = t0 & 4095;

    if (tid < 192) { gs[tid] = g2[tid]; bs[tid] = b2[tid]; }
    __syncthreads();
    if (tid < 512) {
        const int tok = tid >> 2, p = tid & 3;
        const float* rp = x2 + (size_t)(t0 + tok) * DIM + p * 48;
        float xv[48];
        #pragma unroll
        for (int c4 = 0; c4 < 12; ++c4)
            *(float4*)&xv[c4 * 4] = *(const float4*)(rp + c4 * 4);
        float sum = 0.f;
        #pragma unroll
        for (int c = 0; c < 48; ++c) sum += xv[c];
        sum += __shfl_xor(sum, 1);
        sum += __shfl_xor(sum, 2);
        const float m = sum * (1.0f / 192.0f);
        float ss = 0.f;
        #pragma unroll
        for (int c = 0; c < 48; ++c) { float d = xv[c] - m; ss += d * d; }
        ss += __shfl_xor(ss, 1);
        ss += __shfl_xor(ss, 2);
        const float rs = 1.0f / sqrtf(ss * (1.0f / 192.0f) + 1e-5f);
        ushort_t* hp = &h_h[tok][p * 48];
        #pragma unroll
        for (int c2 = 0; c2 < 24; ++c2) {
            float v0 = (xv[2*c2]   - m) * rs * gs[p * 48 + 2*c2]   + bs[p * 48 + 2*c2];
            float v1 = (xv[2*c2+1] - m) * rs * gs[p * 48 + 2*c2+1] + bs[p * 48 + 2*c2+1];
            *(unsigned*)(hp + 2 * c2) = pk2(v0, v1);
        }
    }
    __syncthreads();

    f32x4 acc2[4][2];
    #pragma unroll
    for (int i = 0; i < 4; ++i)
        #pragma unroll
        for (int j = 0; j < 2; ++j)
            acc2[i][j] = (f32x4)(0.0f);

    for (int c = 0; c < 4; ++c) {                 // 4 chunks of 192 fc1-outs
        f32x4 acc1[4][2];
        #pragma unroll
        for (int i = 0; i < 4; ++i)
            #pragma unroll
            for (int j = 0; j < 2; ++j)
                acc1[i][j] = (f32x4)(0.0f);
        const ushort_t* Wb1 = w1f + (size_t)(c * 12 + ow * 2) * 3072 + m16 * 8;
        for (int ks = 0; ks < 192; ks += 32) {
            bf16x8 af[4], wv[2];
            #pragma unroll
            for (int i = 0; i < 4; ++i)
                af[i] = *(const bf16x8*)&h_h[half * 64 + 16 * i + m16][quad * 8 + ks];
            #pragma unroll
            for (int j = 0; j < 2; ++j)
                wv[j] = *(const bf16x8*)(Wb1 + (size_t)(j * 24 + (ks >> 3) + quad) * 128);
            PRIO_HI();
            #pragma unroll
            for (int i = 0; i < 4; ++i)
                #pragma unroll
                for (int j = 0; j < 2; ++j)
                    acc1[i][j] = __builtin_amdgcn_mfma_f32_16x16x32_bf16(wv[j], af[i], acc1[i][j], 0, 0, 0);
            PRIO_LO();
        }
        #pragma unroll
        for (int j = 0; j < 2; ++j) {
            const int o = c * 192 + ow * 32 + 16 * j + quad * 4;
            const float4 bv = *(const float4*)&fc1_b[o];
            #pragma unroll
            for (int i = 0; i < 4; ++i) {
                f32x4 v = acc1[i][j];
                v[0] += bv.x; v[1] += bv.y; v[2] += bv.z; v[3] += bv.w;
                #pragma unroll
                for (int r = 0; r < 4; ++r) {
                    float xg = v[r];
                    float e1 = __expf(xg * (1.5957691f + 0.0713548f * xg * xg)) + 1.0f;
                    v[r] = xg - xg * __builtin_amdgcn_rcpf(e1);
                }
                uint2 pkd;
                pkd.x = pk2(v[0], v[1]); pkd.y = pk2(v[2], v[3]);
                *(uint2*)&a1c[half * 64 + 16 * i + m16][ow * 32 + 16 * j + quad * 4] = pkd;
            }
        }
        __syncthreads();
        const ushort_t* Wb2 = w2f + (size_t)(ow * 2) * 12288 + m16 * 8;
        for (int ks = 0; ks < 192; ks += 32) {
            bf16x8 af2[4], wv2[2];
            #pragma unroll
            for (int i = 0; i < 4; ++i)
                af2[i] = *(const bf16x8*)&a1c[half * 64 + 16 * i + m16][quad * 8 + ks];
            #pragma unroll
            for (int j = 0; j < 2; ++j)
                wv2[j] = *(const bf16x8*)(Wb2 + (size_t)(j * 96 + c * 24 + (ks >> 3) + quad) * 128);
            PRIO_HI();
            #pragma unroll
            for (int i = 0; i < 4; ++i)
                #pragma unroll
                for (int j = 0; j < 2; ++j)
                    acc2[i][j] = __builtin_amdgcn_mfma_f32_16x16x32_bf16(wv2[j], af2[i], acc2[i][j], 0, 0, 0);
            PRIO_LO();
        }
        __syncthreads();
    }

    // ---- epilogue: stage [32 tok][32 outs] per pass, write NCHW with
    //      full 128-B-granule runs (64-token-consecutive per channel). ----
    float* Cw = (float*)(smem + wave * 4608);      // [32][36] f32, overlay
    float4 b2j[2];
    #pragma unroll
    for (int j = 0; j < 2; ++j)
        b2j[j] = *(const float4*)&fc2_b[ow * 32 + 16 * j + quad * 4];
    #pragma unroll
    for (int p = 0; p < 2; ++p) {
        #pragma unroll
        for (int ih = 0; ih < 2; ++ih) {
            const int i = 2 * p + ih;
            #pragma unroll
            for (int j = 0; j < 2; ++j) {
                f32x4 v = acc2[i][j];
                v[0] += b2j[j].x; v[1] += b2j[j].y; v[2] += b2j[j].z; v[3] += b2j[j].w;
                *(f32x4*)&Cw[(ih * 16 + m16) * 36 + 16 * j + quad * 4] = v;
            }
        }
        #pragma unroll
        for (int q = 0; q < 4; ++q) {
            const int idx = q * 64 + lane;
            const int cc = idx >> 3, t4 = (idx & 7) * 4;
            const int o  = ow * 32 + cc;
            const int tb = t0 + half * 64 + p * 32 + t4;
            float4 vv;
            vv.x = Cw[(t4 + 0) * 36 + cc] + x2[(size_t)(tb + 0) * DIM + o];
            vv.y = Cw[(t4 + 1) * 36 + cc] + x2[(size_t)(tb + 1) * DIM + o];
            vv.z = Cw[(t4 + 2) * 36 + cc] + x2[(size_t)(tb + 2) * DIM + o];
            vv.w = Cw[(t4 + 3) * 36 + cc] + x2[(size_t)(tb + 3) * DIM + o];
            *(float4*)&outp[(size_t)b * (DIM * 4096) + (size_t)o * 4096
                            + hw0 + half * 64 + p * 32 + t4] = vv;
        }
    }
}

// ---------------------------------------------------------------------------
extern "C" void kernel_launch(void* const* d_in, const int* in_sizes, int n_in,
                              void* d_out, int out_size, void* d_ws, size_t ws_size,
                              hipStream_t stream)
{
    const float* x        = (const float*)d_in[0];
    const float* norm1_g  = (const float*)d_in[1];
    const float* norm1_b  = (const float*)d_in[2];
    const float* qkv_w    = (const float*)d_in[3];
    const float* qkv_b    = (const float*)d_in[4];
    const float* proj_w   = (const float*)d_in[5];
    const float* proj_b   = (const float*)d_in[6];
    const float* rpbt     = (const float*)d_in[7];
    const float* temp     = (const float*)d_in[8];
    const float* norm2_g  = (const float*)d_in[9];
    const float* norm2_b  = (const float*)d_in[10];
    const float* fc1_w    = (const float*)d_in[11];
    const float* fc1_b    = (const float*)d_in[12];
    const float* fc2_w    = (const float*)d_in[13];
    const float* fc2_b    = (const float*)d_in[14];
    float* out = (float*)d_out;

    // ws layout (bytes):
    //   [0,        12582912)  shortcut bf16 (LN1 out)
    //   [12582912, 37748736)  x2 f32
    //   [125829120,...)       weights bf16 (fragment order; qkv Q/K permuted)
    char* wsb = (char*)d_ws;
    ushort_t* shortcut_h = (ushort_t*)wsb;
    float*    x2         = (float*)(wsb + 12582912);
    ushort_t* wq  = (ushort_t*)(wsb + 125829120);      // 576x192 = 110592
    ushort_t* wp  = wq + 110592;                       // 192x192 = 36864
    ushort_t* w1  = wp + 36864;                        // 768x192 = 147456
    ushort_t* w2  = w1 + 147456;                       // 192x768 = 147456

    // 0+1. merged weight conversion (432 blocks) + LN1 transpose (512 blocks)
    hipLaunchKernelGGL(prep_kernel, dim3(432 + TTOT / 64), dim3(256), 0, stream,
                       qkv_w, proj_w, fc1_w, fc2_w, wq, wp, w1, w2,
                       x, norm1_g, norm1_b, shortcut_h);
    // 2. fused qkv + attention + proj + residual -> x2 (2 windows/block)
    hipLaunchKernelGGL(attn_fused, dim3(NWIN / 2), dim3(768), 0, stream,
                       shortcut_h, wq, qkv_b, rpbt, temp, wp, proj_b, x2);
    // 3. fused LN2 + fc1 + GELU + fc2 + residual + NCHW transpose
    hipLaunchKernelGGL(mlp_fused, dim3(TTOT / 128), dim3(768), 0, stream,
                       x2, w1, w2, fc1_b, fc2_b, norm2_g, norm2_b, out);
}